// Round 14
// baseline (195.311 us; speedup 1.0000x reference)
//
#include <hip/hip_runtime.h>

typedef __bf16 bf16;
typedef unsigned int u32;
typedef __bf16 bf16x8 __attribute__((ext_vector_type(8)));
typedef float f32x4 __attribute__((ext_vector_type(4)));
typedef float f32x16 __attribute__((ext_vector_type(16)));

#define DEV __device__ __forceinline__

// async global->LDS, 16B per lane; lds base must be wave-uniform (HW adds lane*16);
// global source address IS per-lane (m173)
DEV void gload_lds16(const void* g, void* l) {
  __builtin_amdgcn_global_load_lds((const __attribute__((address_space(1))) void*)g,
                                   (__attribute__((address_space(3))) void*)l,
                                   16, 0, 0);
}

DEV u32 pack2(float a, float b) {
  unsigned short ua = __builtin_bit_cast(unsigned short, (bf16)a);
  unsigned short ub = __builtin_bit_cast(unsigned short, (bf16)b);
  return (u32)ua | ((u32)ub << 16);
}

// ---------------- all weight transposes in ONE launch ----------------
__global__ void transpose_all(const float* __restrict__ wq, const float* __restrict__ wk,
                              const float* __restrict__ wv, const float* __restrict__ wo,
                              bf16* __restrict__ wqT, bf16* __restrict__ wkvT,
                              bf16* __restrict__ woT, float scale_q) {
  __shared__ float tile[32][33];
  int x = blockIdx.x;
  const float* in;
  bf16* out;
  int C;
  float scale = 1.0f;
  int c0;
  if (x < 32)      { in = wq; out = wqT;             C = 1024; c0 = x * 32; scale = scale_q; }
  else if (x < 34) { in = wk; out = wkvT;            C = 64;   c0 = (x - 32) * 32; }
  else if (x < 36) { in = wv; out = wkvT + 64 * 1024; C = 64;  c0 = (x - 34) * 32; }
  else             { in = wo; out = woT;             C = 1024; c0 = (x - 36) * 32; }
  int r0 = blockIdx.y * 32;
  int tx = threadIdx.x & 31, ty = threadIdx.x >> 5;  // 256 threads = 32x8
  for (int i = ty; i < 32; i += 8) tile[i][tx] = in[(size_t)(r0 + i) * C + c0 + tx];
  __syncthreads();
  for (int i = ty; i < 32; i += 8)
    out[(size_t)(c0 + i) * 1024 + r0 + tx] = (bf16)(tile[tx][i] * scale);
}

// ---------------- bf16 GEMM, B transposed (Bt[N][K]), 2-phase ----------------
template <typename OutT>
__global__ __launch_bounds__(256)
void gemm_bt(const bf16* __restrict__ A, const bf16* __restrict__ Bt,
             OutT* __restrict__ C, int M, int N, int K) {
  __shared__ __align__(16) bf16 As[2][128 * 32];
  __shared__ __align__(16) bf16 Bs[2][128 * 32];
  const int tid = threadIdx.x;
  const int wid = tid >> 6, lane = tid & 63;
  const int wr = wid >> 1, wc = wid & 1;
  const int lx = lane & 15, g = lane >> 4;
  const size_t bm = (size_t)blockIdx.x * 128;
  const size_t bn = (size_t)blockIdx.y * 128;
  f32x4 acc[4][4] = {};
  const int nk = K >> 5;

  auto stage = [&](int buf, int k0) {
#pragma unroll
    for (int i = 0; i < 2; ++i) {
      int c = i * 256 + wid * 64 + lane;
      const bf16* gp = A + (bm + (size_t)(c >> 2)) * K + k0 + (c & 3) * 8;
      gload_lds16(gp, (char*)As[buf] + (size_t)(i * 256 + wid * 64) * 16);
    }
#pragma unroll
    for (int i = 0; i < 2; ++i) {
      int c = i * 256 + wid * 64 + lane;
      const bf16* gp = Bt + (bn + (size_t)(c >> 2)) * K + k0 + (c & 3) * 8;
      gload_lds16(gp, (char*)Bs[buf] + (size_t)(i * 256 + wid * 64) * 16);
    }
  };

  stage(0, 0);
  __syncthreads();
  int cur = 0;

  for (int t = 0; t < nk; ++t) {
    if (t + 1 < nk) stage(cur ^ 1, (t + 1) * 32);

    bf16x8 af[4], bfr[4];
#pragma unroll
    for (int m = 0; m < 4; ++m)
      af[m] = *(const bf16x8*)&As[cur][(wr * 64 + m * 16 + lx) * 32 + g * 8];
#pragma unroll
    for (int n = 0; n < 4; ++n)
      bfr[n] = *(const bf16x8*)&Bs[cur][(wc * 64 + n * 16 + lx) * 32 + g * 8];
#pragma unroll
    for (int m = 0; m < 4; ++m)
#pragma unroll
      for (int n = 0; n < 4; ++n)
        acc[m][n] = __builtin_amdgcn_mfma_f32_16x16x32_bf16(af[m], bfr[n], acc[m][n], 0, 0, 0);

    __syncthreads();  // drains t+1 staging (after compute) + readers done with cur
    cur ^= 1;
  }

#pragma unroll
  for (int m = 0; m < 4; ++m)
#pragma unroll
    for (int n = 0; n < 4; ++n) {
      size_t row = bm + wr * 64 + m * 16 + g * 4;
      size_t col = bn + wc * 64 + n * 16 + lx;
#pragma unroll
      for (int j = 0; j < 4; ++j)
        C[(row + j) * N + col] = (OutT)acc[m][n][j];
    }
}

// ---------------- fused cast+projections: q = Q@wq ; [k|v] = [K;V]@[wk|wv] --------
// 2-phase + T14 split on the reg-staged A path.
__global__ __launch_bounds__(256)
void proj_kernel(const float* __restrict__ Qf, const float* __restrict__ Kf,
                 const float* __restrict__ Vf, const bf16* __restrict__ wqT,
                 const bf16* __restrict__ wkvT, bf16* __restrict__ qp,
                 bf16* __restrict__ kp, bf16* __restrict__ vTp) {
  const int bid = blockIdx.x;
  const bool isq = bid < 512;
  const float* Af;
  size_t arow, bm, bn;
  const bf16* Bt = isq ? wqT : wkvT;
  if (isq) {
    bm = (size_t)(bid & 63) * 128;
    arow = bm;
    bn = (size_t)(bid >> 6) * 128;
    Af = Qf;
  } else {
    int kv = bid - 512;  // 0..127 rows of stacked [K;V]
    bm = (size_t)kv * 128;
    bn = 0;
    if (kv < 64) { Af = Kf; arow = bm; } else { Af = Vf; arow = bm - 8192; }
  }

  __shared__ __align__(16) bf16 As[2][128 * 32];
  __shared__ __align__(16) bf16 Bs[2][128 * 32];
  const int tid = threadIdx.x;
  const int wid = tid >> 6, lane = tid & 63;
  const int wr = wid >> 1, wc = wid & 1;
  const int lx = lane & 15, g = lane >> 4;
  f32x4 acc[4][4] = {};

  auto loadA = [&](int k0, float4 (&ar)[2][2]) {
#pragma unroll
    for (int i = 0; i < 2; ++i) {
      int c = i * 256 + tid;
      const float* src = Af + (arow + (size_t)(c >> 2)) * 1024 + k0 + (c & 3) * 8;
      ar[i][0] = *(const float4*)src;
      ar[i][1] = *(const float4*)(src + 4);
    }
  };
  auto writeA = [&](int buf, const float4 (&ar)[2][2]) {
#pragma unroll
    for (int i = 0; i < 2; ++i) {
      bf16x8 v;
      v[0] = (bf16)ar[i][0].x; v[1] = (bf16)ar[i][0].y;
      v[2] = (bf16)ar[i][0].z; v[3] = (bf16)ar[i][0].w;
      v[4] = (bf16)ar[i][1].x; v[5] = (bf16)ar[i][1].y;
      v[6] = (bf16)ar[i][1].z; v[7] = (bf16)ar[i][1].w;
      *(bf16x8*)((char*)As[buf] + (size_t)(i * 256 + tid) * 16) = v;
    }
  };
  auto stageB = [&](int buf, int k0) {
#pragma unroll
    for (int i = 0; i < 2; ++i) {
      int c = i * 256 + wid * 64 + lane;
      const bf16* gp = Bt + (bn + (size_t)(c >> 2)) * 1024 + k0 + (c & 3) * 8;
      gload_lds16(gp, (char*)Bs[buf] + (size_t)(i * 256 + wid * 64) * 16);
    }
  };

  // prologue: tile 0
  {
    float4 ar[2][2];
    loadA(0, ar);
    stageB(0, 0);
    writeA(0, ar);
  }
  __syncthreads();
  int cur = 0;

  for (int t = 0; t < 32; ++t) {
    float4 ar[2][2];
    const bool more = t + 1 < 32;
    if (more) {
      loadA((t + 1) * 32, ar);   // issue fp32 loads early (T14)
      stageB(cur ^ 1, (t + 1) * 32);
    }

    bf16x8 af[4], bfr[4];
#pragma unroll
    for (int m = 0; m < 4; ++m)
      af[m] = *(const bf16x8*)&As[cur][(wr * 64 + m * 16 + lx) * 32 + g * 8];
#pragma unroll
    for (int n = 0; n < 4; ++n)
      bfr[n] = *(const bf16x8*)&Bs[cur][(wc * 64 + n * 16 + lx) * 32 + g * 8];
#pragma unroll
    for (int m = 0; m < 4; ++m)
#pragma unroll
      for (int n = 0; n < 4; ++n)
        acc[m][n] = __builtin_amdgcn_mfma_f32_16x16x32_bf16(af[m], bfr[n], acc[m][n], 0, 0, 0);

    if (more) writeA(cur ^ 1, ar);  // vmcnt wait + convert AFTER compute

    __syncthreads();  // drains B staging + A writes; readers done with cur
    cur ^= 1;
  }

#pragma unroll
  for (int m = 0; m < 4; ++m)
#pragma unroll
    for (int n = 0; n < 4; ++n) {
      size_t row = bm + wr * 64 + m * 16 + g * 4;
      size_t col = bn + wc * 64 + n * 16 + lx;
#pragma unroll
      for (int j = 0; j < 4; ++j) {
        float v = acc[m][n][j];
        size_t r = row + j;
        if (isq) {
          qp[r * 1024 + col] = (bf16)v;
        } else if (col < 64) {
          if (r < 8192) kp[r * 64 + col] = (bf16)v;  // [b*2048+key][64]
        } else {
          if (r >= 8192) {
            size_t rr = r - 8192;
            size_t bb = rr >> 11, nn = rr & 2047;
            vTp[bb * 131072 + (nn >> 5) * 2048 + (col - 64) * 32 + (nn & 31)] = (bf16)v;
          }
        }
      }
    }
}

// ---------------- causal multi-query flash attention ----------------
// ROUND 14: grid (32 strip-pairs, 8 head-groups, 4 batch) = 1024 blocks, 128
// threads = 2 waves = 2 HEADS sharing K/V LDS. 1024 blocks = exactly 4/CU, each
// CU holds 4 INDEPENDENT barrier groups (phase diversity fills the ~45% dead time
// seen at 2 blocks/CU). bc[] LDS broadcast replaced by __shfl(., row) (m,l are
// lane-symmetric across the 32-boundary) -> LDS exactly 32KB -> 4 blocks fit even
// under a 128KB schedulable limit. Round body = verified round-8/12 path.
__global__ __launch_bounds__(128, 4)
void attn_kernel(const bf16* __restrict__ q, const bf16* __restrict__ k,
                 const bf16* __restrict__ vt, bf16* __restrict__ o) {
  const int hg = blockIdx.y, b = blockIdx.z;
  const int wid = threadIdx.x >> 6, lane = threadIdx.x & 63;
  const int lq = lane & 31, hi = lane >> 5;
  const int h = hg * 2 + wid;
  const int pairIdx = blockIdx.x;  // 0..31

  __shared__ __align__(16) char Ks[2][8192];  // 2 x 4KB subtiles (32 keys x 64d each)
  __shared__ __align__(16) char Vs[2][8192];  // 2 x 4KB subtiles (64d x 32 keys each)

  const bf16* kb = k + (size_t)b * 2048 * 64;                // [key][64]
  const char* vbase = (const char*)vt + (size_t)b * 262144;  // [tile][d][key32]

  // stage one 4KB tile with 2 waves: 2 granule-groups of 1KB per wave; the XOR
  // swizzles depend only on lane bits 3-5, so the mapping is identical to the
  // 4-wave version (rule 21: swizzle at SOURCE, matched at ds_read).
  auto stageK = [&](int bi, int kt, int sub) {
#pragma unroll
    for (int i = 0; i < 2; ++i) {
      int src = (i * 128 + wid * 64 + lane) ^ ((lane >> 3) & 7);
      gload_lds16((const char*)(kb + (size_t)kt * 2048) + src * 16,
                  &Ks[bi][sub * 4096 + (i * 2 + wid) * 1024]);
    }
  };
  auto stageV = [&](int bi, int kt, int sub) {
#pragma unroll
    for (int i = 0; i < 2; ++i) {
      int gg = i * 128 + wid * 64 + lane;
      int src = (gg & ~3) | ((gg & 3) ^ ((lane >> 3) & 3));
      gload_lds16(vbase + (size_t)kt * 4096 + src * 16,
                  &Vs[bi][sub * 4096 + (i * 2 + wid) * 1024]);
    }
  };

  bf16x8 qf[4];

  // QK^T for one 32-key subtile: S^T[key][q], lane holds 16 scores of query lq,
  // key = base + (r&3)+8*(r>>2)+4*hi
  auto qkt = [&](int cur, int sub) -> f32x16 {
    bf16x8 kf[4];
#pragma unroll
    for (int i = 0; i < 4; ++i)
      kf[i] = *(const bf16x8*)&Ks[cur][sub * 4096 + ((lq * 8 + i * 2 + hi) ^ (lq & 7)) * 16];
    f32x16 S = {};
#pragma unroll
    for (int i = 0; i < 4; ++i)
      S = __builtin_amdgcn_mfma_f32_32x32x16_bf16(kf[i], qf[i], S, 0, 0, 0);
    return S;
  };
  auto loadV = [&](int cur, int sub, bf16x8 (&vf)[2][2]) {
#pragma unroll
    for (int d = 0; d < 2; ++d)
#pragma unroll
      for (int ks = 0; ks < 2; ++ks)
        vf[d][ks] = *(const bf16x8*)&Vs[cur][sub * 4096 +
                        ((d * 32 + lq) * 4 + ((ks * 2 + hi) ^ ((lq >> 1) & 3))) * 16];
  };
  // rebuild PV A-fragments from 8 packed words (verified round-2 path)
  auto rebuild = [&](const u32 w[8], bf16x8& o0, bf16x8& o1) {
    u32 sw0 = (u32)__shfl_xor((int)w[0], 32), sw1 = (u32)__shfl_xor((int)w[1], 32);
    u32 sw2 = (u32)__shfl_xor((int)w[2], 32), sw3 = (u32)__shfl_xor((int)w[3], 32);
    u32 sw4 = (u32)__shfl_xor((int)w[4], 32), sw5 = (u32)__shfl_xor((int)w[5], 32);
    u32 sw6 = (u32)__shfl_xor((int)w[6], 32), sw7 = (u32)__shfl_xor((int)w[7], 32);
    union { u32 d[4]; bf16x8 v; } f0, f1;
    f0.d[0] = hi ? sw2 : w[0];
    f0.d[1] = hi ? sw3 : w[1];
    f0.d[2] = hi ? w[2] : sw0;
    f0.d[3] = hi ? w[3] : sw1;
    f1.d[0] = hi ? sw6 : w[4];
    f1.d[1] = hi ? sw7 : w[5];
    f1.d[2] = hi ? w[6] : sw4;
    f1.d[3] = hi ? w[7] : sw5;
    o0 = f0.v;
    o1 = f1.v;
  };

#pragma unroll 1
  for (int rep = 0; rep < 2; ++rep) {
    const int strip = rep ? pairIdx : 63 - pairIdx;
    const int qb = strip * 32;
    const int nt = strip + 1;
    const int nfull = nt >> 1, tail = nt & 1;

    const bf16* qrow = q + (size_t)(b * 2048 + qb + lq) * 1024 + h * 64 + hi * 8;
#pragma unroll
    for (int i = 0; i < 4; ++i) qf[i] = *(const bf16x8*)(qrow + i * 16);

    f32x16 O0 = {}, O1 = {};
    float m = -__builtin_inff(), l = 0.f;

    __syncthreads();  // previous rep's readers done before restaging buffers
    if (nfull) {
      stageK(0, 0, 0); stageK(0, 1, 1);
      stageV(0, 0, 0); stageV(0, 1, 1);
    } else {
      stageK(0, 0, 0); stageV(0, 0, 0);
    }
    __syncthreads();
    int cur = 0;

    for (int r2 = 0; r2 < nfull; ++r2) {
      if (r2 + 1 < nfull) {
        stageK(cur ^ 1, 2 * r2 + 2, 0); stageK(cur ^ 1, 2 * r2 + 3, 1);
        stageV(cur ^ 1, 2 * r2 + 2, 0); stageV(cur ^ 1, 2 * r2 + 3, 1);
      } else if (tail) {
        stageK(cur ^ 1, 2 * nfull, 0); stageV(cur ^ 1, 2 * nfull, 0);
      }

      __builtin_amdgcn_s_setprio(1);
      f32x16 SA = qkt(cur, 0);
      f32x16 SB = qkt(cur, 1);
      __builtin_amdgcn_s_setprio(0);

      if (r2 == nfull - 1 && !tail) {  // subtile B is the diagonal tile
#pragma unroll
        for (int r = 0; r < 16; ++r) {
          int kr = (r & 3) + 8 * (r >> 2) + 4 * hi;
          if (kr > lq) SB[r] = -__builtin_inff();
        }
      }

      // joint row max over 32 scores
      float pm = fmaxf(fmaxf(SA[0], SA[1]), SA[2]);
      pm = fmaxf(fmaxf(pm, SA[3]), SA[4]);
      pm = fmaxf(fmaxf(pm, SA[5]), SA[6]);
      pm = fmaxf(fmaxf(pm, SA[7]), SA[8]);
      pm = fmaxf(fmaxf(pm, SA[9]), SA[10]);
      pm = fmaxf(fmaxf(pm, SA[11]), SA[12]);
      pm = fmaxf(fmaxf(pm, SA[13]), SA[14]);
      pm = fmaxf(fmaxf(pm, SA[15]), SB[0]);
      pm = fmaxf(fmaxf(pm, SB[1]), SB[2]);
      pm = fmaxf(fmaxf(pm, SB[3]), SB[4]);
      pm = fmaxf(fmaxf(pm, SB[5]), SB[6]);
      pm = fmaxf(fmaxf(pm, SB[7]), SB[8]);
      pm = fmaxf(fmaxf(pm, SB[9]), SB[10]);
      pm = fmaxf(fmaxf(pm, SB[11]), SB[12]);
      pm = fmaxf(fmaxf(pm, SB[13]), SB[14]);
      pm = fmaxf(pm, SB[15]);
      pm = fmaxf(pm, __shfl_xor(pm, 32));

      if (!__all(pm <= m + 8.0f)) {  // rescale path (rare after warmup)
        float mn = fmaxf(m, pm);
        float fac = __builtin_amdgcn_exp2f(m - mn);
        m = mn;
        l *= fac;
#pragma unroll
        for (int r = 0; r < 16; ++r) {
          float fr = __shfl(fac, (r & 3) + 8 * (r >> 2) + 4 * hi);
          O0[r] *= fr;
          O1[r] *= fr;
        }
      }

      float lsA = 0.f, lsB = 0.f;
      u32 wA[8], wB[8];
#pragma unroll
      for (int i = 0; i < 8; ++i) {
        float e0 = __builtin_amdgcn_exp2f(SA[2 * i] - m);
        float e1 = __builtin_amdgcn_exp2f(SA[2 * i + 1] - m);
        lsA += e0 + e1;
        wA[i] = pack2(e0, e1);
      }
#pragma unroll
      for (int i = 0; i < 8; ++i) {
        float e0 = __builtin_amdgcn_exp2f(SB[2 * i] - m);
        float e1 = __builtin_amdgcn_exp2f(SB[2 * i + 1] - m);
        lsB += e0 + e1;
        wB[i] = pack2(e0, e1);
      }
      float ls = lsA + lsB;
      ls += __shfl_xor(ls, 32);
      l += ls;

      bf16x8 f0A, f1A, f0B, f1B;
      rebuild(wA, f0A, f1A);
      rebuild(wB, f0B, f1B);

      bf16x8 vfA[2][2], vfB[2][2];
      loadV(cur, 0, vfA);
      loadV(cur, 1, vfB);

      __builtin_amdgcn_s_setprio(1);
      O0 = __builtin_amdgcn_mfma_f32_32x32x16_bf16(f0A, vfA[0][0], O0, 0, 0, 0);
      O0 = __builtin_amdgcn_mfma_f32_32x32x16_bf16(f1A, vfA[0][1], O0, 0, 0, 0);
      O0 = __builtin_amdgcn_mfma_f32_32x32x16_bf16(f0B, vfB[0][0], O0, 0, 0, 0);
      O0 = __builtin_amdgcn_mfma_f32_32x32x16_bf16(f1B, vfB[0][1], O0, 0, 0, 0);
      O1 = __builtin_amdgcn_mfma_f32_32x32x16_bf16(f0A, vfA[1][0], O1, 0, 0, 0);
      O1 = __builtin_amdgcn_mfma_f32_32x32x16_bf16(f1A, vfA[1][1], O1, 0, 0, 0);
      O1 = __builtin_amdgcn_mfma_f32_32x32x16_bf16(f0B, vfB[1][0], O1, 0, 0, 0);
      O1 = __builtin_amdgcn_mfma_f32_32x32x16_bf16(f1B, vfB[1][1], O1, 0, 0, 0);
      __builtin_amdgcn_s_setprio(0);

      __syncthreads();  // own staging drained + all waves done reading
      cur ^= 1;
    }

    if (tail) {  // final 32-key diagonal tile (nt odd), staged in buffer `cur` sub 0
      __builtin_amdgcn_s_setprio(1);
      f32x16 S = qkt(cur, 0);
      __builtin_amdgcn_s_setprio(0);
#pragma unroll
      for (int r = 0; r < 16; ++r) {
        int kr = (r & 3) + 8 * (r >> 2) + 4 * hi;
        if (kr > lq) S[r] = -__builtin_inff();
      }
      float pm = fmaxf(fmaxf(S[0], S[1]), S[2]);
      pm = fmaxf(fmaxf(pm, S[3]), S[4]);
      pm = fmaxf(fmaxf(pm, S[5]), S[6]);
      pm = fmaxf(fmaxf(pm, S[7]), S[8]);
      pm = fmaxf(fmaxf(pm, S[9]), S[10]);
      pm = fmaxf(fmaxf(pm, S[11]), S[12]);
      pm = fmaxf(fmaxf(pm, S[13]), S[14]);
      pm = fmaxf(pm, S[15]);
      pm = fmaxf(pm, __shfl_xor(pm, 32));

      if (!__all(pm <= m + 8.0f)) {
        float mn = fmaxf(m, pm);
        float fac = __builtin_amdgcn_exp2f(m - mn);
        m = mn;
        l *= fac;
#pragma unroll
        for (int r = 0; r < 16; ++r) {
          float fr = __shfl(fac, (r & 3) + 8 * (r >> 2) + 4 * hi);
          O0[r] *= fr;
          O1[r] *= fr;
        }
      }

      float ls = 0.f;
      u32 w[8];
#pragma unroll
      for (int i = 0; i < 8; ++i) {
        float e0 = __builtin_amdgcn_exp2f(S[2 * i] - m);
        float e1 = __builtin_amdgcn_exp2f(S[2 * i + 1] - m);
        ls += e0 + e1;
        w[i] = pack2(e0, e1);
      }
      ls += __shfl_xor(ls, 32);
      l += ls;

      bf16x8 f0, f1;
      rebuild(w, f0, f1);
      bf16x8 vf[2][2];
      loadV(cur, 0, vf);

      __builtin_amdgcn_s_setprio(1);
      O0 = __builtin_amdgcn_mfma_f32_32x32x16_bf16(f0, vf[0][0], O0, 0, 0, 0);
      O0 = __builtin_amdgcn_mfma_f32_32x32x16_bf16(f1, vf[0][1], O0, 0, 0, 0);
      O1 = __builtin_amdgcn_mfma_f32_32x32x16_bf16(f0, vf[1][0], O1, 0, 0, 0);
      O1 = __builtin_amdgcn_mfma_f32_32x32x16_bf16(f1, vf[1][1], O1, 0, 0, 0);
      __builtin_amdgcn_s_setprio(0);
    }

    // epilogue: normalize by 1/l (per-row broadcast via shfl) and store
    float linv = 1.0f / l;
#pragma unroll
    for (int r = 0; r < 16; ++r) {
      int row = (r & 3) + 8 * (r >> 2) + 4 * hi;
      float sc = __shfl(linv, row);
      size_t base = (size_t)(b * 2048 + qb + row) * 1024 + h * 64;
      o[base + lq] = (bf16)(O0[r] * sc);
      o[base + 32 + lq] = (bf16)(O1[r] * sc);
    }
  }
}

// ---------------- launch ----------------
extern "C" void kernel_launch(void* const* d_in, const int* in_sizes, int n_in,
                              void* d_out, int out_size, void* d_ws, size_t ws_size,
                              hipStream_t stream) {
  const float* Q  = (const float*)d_in[0];
  const float* K  = (const float*)d_in[1];
  const float* V  = (const float*)d_in[2];
  const float* wq = (const float*)d_in[3];
  const float* wk = (const float*)d_in[4];
  const float* wv = (const float*)d_in[5];
  const float* wo = (const float*)d_in[6];
  float* out = (float*)d_out;

  char* ws = (char*)d_ws;
  bf16* qp   = (bf16*)(ws + (48ull << 20));          // q proj bf16, 16 MB
  bf16* ab   = (bf16*)(ws + (64ull << 20));          // attn out bf16, 16 MB
  bf16* kp   = (bf16*)(ws + (80ull << 20));          // [b][key][64], 1 MB
  bf16* vTp  = (bf16*)(ws + (81ull << 20));          // [b][tile][d][key32], 1 MB
  bf16* wqT  = (bf16*)(ws + (82ull << 20));          // 2 MB
  bf16* woT  = (bf16*)(ws + (84ull << 20));          // 2 MB
  bf16* wkvT = (bf16*)(ws + (86ull << 20));          // [128][1024] = 256 KB

  // fold softmax scale (1/sqrt(64)) and log2(e) into Wq (exp2-based softmax)
  const float SCALE = 0.125f * 1.44269504088896340736f;
  transpose_all<<<dim3(68, 32), 256, 0, stream>>>(wq, wk, wv, wo, wqT, wkvT, woT, SCALE);

  proj_kernel<<<640, 256, 0, stream>>>(Q, K, V, wqT, wkvT, qp, kp, vTp);

  attn_kernel<<<dim3(32, 8, 4), 128, 0, stream>>>(qp, kp, vTp, ab);

  gemm_bt<float><<<dim3(64, 8), 256, 0, stream>>>(ab, woT, out, 8192, 1024, 1024);
}

// Round 15
// 153.741 us; speedup vs baseline: 1.2704x; 1.2704x over previous
//
#include <hip/hip_runtime.h>

typedef __bf16 bf16;
typedef unsigned int u32;
typedef __bf16 bf16x8 __attribute__((ext_vector_type(8)));
typedef float f32x4 __attribute__((ext_vector_type(4)));
typedef float f32x16 __attribute__((ext_vector_type(16)));

#define DEV __device__ __forceinline__

// async global->LDS, 16B per lane; lds base must be wave-uniform (HW adds lane*16);
// global source address IS per-lane (m173)
DEV void gload_lds16(const void* g, void* l) {
  __builtin_amdgcn_global_load_lds((const __attribute__((address_space(1))) void*)g,
                                   (__attribute__((address_space(3))) void*)l,
                                   16, 0, 0);
}

DEV u32 pack2(float a, float b) {
  unsigned short ua = __builtin_bit_cast(unsigned short, (bf16)a);
  unsigned short ub = __builtin_bit_cast(unsigned short, (bf16)b);
  return (u32)ua | ((u32)ub << 16);
}

// ---------------- all weight transposes in ONE launch ----------------
__global__ void transpose_all(const float* __restrict__ wq, const float* __restrict__ wk,
                              const float* __restrict__ wv, const float* __restrict__ wo,
                              bf16* __restrict__ wqT, bf16* __restrict__ wkvT,
                              bf16* __restrict__ woT, float scale_q) {
  __shared__ float tile[32][33];
  int x = blockIdx.x;
  const float* in;
  bf16* out;
  int C;
  float scale = 1.0f;
  int c0;
  if (x < 32)      { in = wq; out = wqT;             C = 1024; c0 = x * 32; scale = scale_q; }
  else if (x < 34) { in = wk; out = wkvT;            C = 64;   c0 = (x - 32) * 32; }
  else if (x < 36) { in = wv; out = wkvT + 64 * 1024; C = 64;  c0 = (x - 34) * 32; }
  else             { in = wo; out = woT;             C = 1024; c0 = (x - 36) * 32; }
  int r0 = blockIdx.y * 32;
  int tx = threadIdx.x & 31, ty = threadIdx.x >> 5;  // 256 threads = 32x8
  for (int i = ty; i < 32; i += 8) tile[i][tx] = in[(size_t)(r0 + i) * C + c0 + tx];
  __syncthreads();
  for (int i = ty; i < 32; i += 8)
    out[(size_t)(c0 + i) * 1024 + r0 + tx] = (bf16)(tile[tx][i] * scale);
}

// ---------------- bf16 GEMM, B transposed (Bt[N][K]) ----------------
// 2-PHASE: LDS double-buffered; stage tile t+1 BEFORE compute of tile t;
// ONE __syncthreads per K-step (its implicit vmcnt(0) drains the t+1 staging AFTER
// the MFMAs -- staging latency hides under compute).
template <typename OutT>
__global__ __launch_bounds__(256)
void gemm_bt(const bf16* __restrict__ A, const bf16* __restrict__ Bt,
             OutT* __restrict__ C, int M, int N, int K) {
  __shared__ __align__(16) bf16 As[2][128 * 32];
  __shared__ __align__(16) bf16 Bs[2][128 * 32];
  const int tid = threadIdx.x;
  const int wid = tid >> 6, lane = tid & 63;
  const int wr = wid >> 1, wc = wid & 1;
  const int lx = lane & 15, g = lane >> 4;
  const size_t bm = (size_t)blockIdx.x * 128;
  const size_t bn = (size_t)blockIdx.y * 128;
  f32x4 acc[4][4] = {};
  const int nk = K >> 5;

  auto stage = [&](int buf, int k0) {
#pragma unroll
    for (int i = 0; i < 2; ++i) {
      int c = i * 256 + wid * 64 + lane;
      const bf16* gp = A + (bm + (size_t)(c >> 2)) * K + k0 + (c & 3) * 8;
      gload_lds16(gp, (char*)As[buf] + (size_t)(i * 256 + wid * 64) * 16);
    }
#pragma unroll
    for (int i = 0; i < 2; ++i) {
      int c = i * 256 + wid * 64 + lane;
      const bf16* gp = Bt + (bn + (size_t)(c >> 2)) * K + k0 + (c & 3) * 8;
      gload_lds16(gp, (char*)Bs[buf] + (size_t)(i * 256 + wid * 64) * 16);
    }
  };

  stage(0, 0);
  __syncthreads();
  int cur = 0;

  for (int t = 0; t < nk; ++t) {
    if (t + 1 < nk) stage(cur ^ 1, (t + 1) * 32);

    bf16x8 af[4], bfr[4];
#pragma unroll
    for (int m = 0; m < 4; ++m)
      af[m] = *(const bf16x8*)&As[cur][(wr * 64 + m * 16 + lx) * 32 + g * 8];
#pragma unroll
    for (int n = 0; n < 4; ++n)
      bfr[n] = *(const bf16x8*)&Bs[cur][(wc * 64 + n * 16 + lx) * 32 + g * 8];
#pragma unroll
    for (int m = 0; m < 4; ++m)
#pragma unroll
      for (int n = 0; n < 4; ++n)
        acc[m][n] = __builtin_amdgcn_mfma_f32_16x16x32_bf16(af[m], bfr[n], acc[m][n], 0, 0, 0);

    __syncthreads();  // drains t+1 staging (after compute) + readers done with cur
    cur ^= 1;
  }

#pragma unroll
  for (int m = 0; m < 4; ++m)
#pragma unroll
    for (int n = 0; n < 4; ++n) {
      size_t row = bm + wr * 64 + m * 16 + g * 4;
      size_t col = bn + wc * 64 + n * 16 + lx;
#pragma unroll
      for (int j = 0; j < 4; ++j)
        C[(row + j) * N + col] = (OutT)acc[m][n][j];
    }
}

// ---------------- fused cast+projections: q = Q@wq ; [k|v] = [K;V]@[wk|wv] --------
// 2-PHASE + T14 split on A: fp32 loads for t+1 issue BEFORE the MFMAs, the
// convert+ds_write lands AFTER them (HBM latency hides under compute). B double-
// buffered via global_load_lds. One __syncthreads per K-step.
__global__ __launch_bounds__(256)
void proj_kernel(const float* __restrict__ Qf, const float* __restrict__ Kf,
                 const float* __restrict__ Vf, const bf16* __restrict__ wqT,
                 const bf16* __restrict__ wkvT, bf16* __restrict__ qp,
                 bf16* __restrict__ kp, bf16* __restrict__ vTp) {
  const int bid = blockIdx.x;
  const bool isq = bid < 512;
  const float* Af;
  size_t arow, bm, bn;
  const bf16* Bt = isq ? wqT : wkvT;
  if (isq) {
    bm = (size_t)(bid & 63) * 128;
    arow = bm;
    bn = (size_t)(bid >> 6) * 128;
    Af = Qf;
  } else {
    int kv = bid - 512;  // 0..127 rows of stacked [K;V]
    bm = (size_t)kv * 128;
    bn = 0;
    if (kv < 64) { Af = Kf; arow = bm; } else { Af = Vf; arow = bm - 8192; }
  }

  __shared__ __align__(16) bf16 As[2][128 * 32];
  __shared__ __align__(16) bf16 Bs[2][128 * 32];
  const int tid = threadIdx.x;
  const int wid = tid >> 6, lane = tid & 63;
  const int wr = wid >> 1, wc = wid & 1;
  const int lx = lane & 15, g = lane >> 4;
  f32x4 acc[4][4] = {};

  auto loadA = [&](int k0, float4 (&ar)[2][2]) {
#pragma unroll
    for (int i = 0; i < 2; ++i) {
      int c = i * 256 + tid;
      const float* src = Af + (arow + (size_t)(c >> 2)) * 1024 + k0 + (c & 3) * 8;
      ar[i][0] = *(const float4*)src;
      ar[i][1] = *(const float4*)(src + 4);
    }
  };
  auto writeA = [&](int buf, const float4 (&ar)[2][2]) {
#pragma unroll
    for (int i = 0; i < 2; ++i) {
      bf16x8 v;
      v[0] = (bf16)ar[i][0].x; v[1] = (bf16)ar[i][0].y;
      v[2] = (bf16)ar[i][0].z; v[3] = (bf16)ar[i][0].w;
      v[4] = (bf16)ar[i][1].x; v[5] = (bf16)ar[i][1].y;
      v[6] = (bf16)ar[i][1].z; v[7] = (bf16)ar[i][1].w;
      *(bf16x8*)((char*)As[buf] + (size_t)(i * 256 + tid) * 16) = v;
    }
  };
  auto stageB = [&](int buf, int k0) {
#pragma unroll
    for (int i = 0; i < 2; ++i) {
      int c = i * 256 + wid * 64 + lane;
      const bf16* gp = Bt + (bn + (size_t)(c >> 2)) * 1024 + k0 + (c & 3) * 8;
      gload_lds16(gp, (char*)Bs[buf] + (size_t)(i * 256 + wid * 64) * 16);
    }
  };

  // prologue: tile 0
  {
    float4 ar[2][2];
    loadA(0, ar);
    stageB(0, 0);
    writeA(0, ar);
  }
  __syncthreads();
  int cur = 0;

  for (int t = 0; t < 32; ++t) {
    float4 ar[2][2];
    const bool more = t + 1 < 32;
    if (more) {
      loadA((t + 1) * 32, ar);   // issue fp32 loads early (T14)
      stageB(cur ^ 1, (t + 1) * 32);
    }

    bf16x8 af[4], bfr[4];
#pragma unroll
    for (int m = 0; m < 4; ++m)
      af[m] = *(const bf16x8*)&As[cur][(wr * 64 + m * 16 + lx) * 32 + g * 8];
#pragma unroll
    for (int n = 0; n < 4; ++n)
      bfr[n] = *(const bf16x8*)&Bs[cur][(wc * 64 + n * 16 + lx) * 32 + g * 8];
#pragma unroll
    for (int m = 0; m < 4; ++m)
#pragma unroll
      for (int n = 0; n < 4; ++n)
        acc[m][n] = __builtin_amdgcn_mfma_f32_16x16x32_bf16(af[m], bfr[n], acc[m][n], 0, 0, 0);

    if (more) writeA(cur ^ 1, ar);  // vmcnt wait + convert AFTER compute

    __syncthreads();  // drains B staging + A writes; readers done with cur
    cur ^= 1;
  }

#pragma unroll
  for (int m = 0; m < 4; ++m)
#pragma unroll
    for (int n = 0; n < 4; ++n) {
      size_t row = bm + wr * 64 + m * 16 + g * 4;
      size_t col = bn + wc * 64 + n * 16 + lx;
#pragma unroll
      for (int j = 0; j < 4; ++j) {
        float v = acc[m][n][j];
        size_t r = row + j;
        if (isq) {
          qp[r * 1024 + col] = (bf16)v;
        } else if (col < 64) {
          if (r < 8192) kp[r * 64 + col] = (bf16)v;  // [b*2048+key][64]
        } else {
          if (r >= 8192) {
            size_t rr = r - 8192;
            size_t bb = rr >> 11, nn = rr & 2047;
            vTp[bb * 131072 + (nn >> 5) * 2048 + (col - 64) * 32 + (nn & 31)] = (bf16)v;
          }
        }
      }
    }
}

// ---------------- causal multi-query flash attention (round-8 verified config) ----
// grid (32 strip-pairs, 4 head-groups, 4 batch) = 512 blocks, 4 waves = 4 HEADS
// sharing one (strip,batch) [uniform pairing: rep 0 = strip 63-p (long), rep 1 = p].
// K/V staged once/block to LDS (dbuf, XOR-swizzled both sides). KVBLK=64: two
// 32-key subtiles per barrier round; odd tile via 32-key diagonal tail. setprio(1)
// around MFMA clusters (T5). Softmax in-register (verified round-2 path).
// Best measured attn config: 79.5-80.3 us (rounds 8/12/13). All occupancy levers
// measured flat/negative: split-K (r9-11), 2-head/1024-block (r14: 120us, VGPR 136,
// MfmaUtil 11.7). Work-efficiency levers (LDS K/V sharing, KVBLK=64, setprio) won.
__global__ __launch_bounds__(256, 2)
void attn_kernel(const bf16* __restrict__ q, const bf16* __restrict__ k,
                 const bf16* __restrict__ vt, bf16* __restrict__ o) {
  const int hg = blockIdx.y, b = blockIdx.z;
  const int wid = threadIdx.x >> 6, lane = threadIdx.x & 63;
  const int lq = lane & 31, hi = lane >> 5;
  const int h = hg * 4 + wid;
  const int pairIdx = blockIdx.x;  // 0..31

  __shared__ __align__(16) char Ks[2][8192];  // 2 x 4KB subtiles (32 keys x 64d each)
  __shared__ __align__(16) char Vs[2][8192];  // 2 x 4KB subtiles (64d x 32 keys each)
  __shared__ float bc[4][32];

  const bf16* kb = k + (size_t)b * 2048 * 64;                // [key][64]
  const char* vbase = (const char*)vt + (size_t)b * 262144;  // [tile][d][key32]

  // stage one 4KB K tile kt into buffer bi, subtile sub (swizzle at SOURCE, rule 21)
  auto stageK = [&](int bi, int kt, int sub) {
    int src = (wid * 64 + lane) ^ ((lane >> 3) & 7);
    gload_lds16((const char*)(kb + (size_t)kt * 2048) + src * 16,
                &Ks[bi][sub * 4096 + wid * 1024]);
  };
  auto stageV = [&](int bi, int kt, int sub) {
    int g = wid * 64 + lane;
    int src = (g & ~3) | ((g & 3) ^ ((lane >> 3) & 3));
    gload_lds16(vbase + (size_t)kt * 4096 + src * 16, &Vs[bi][sub * 4096 + wid * 1024]);
  };

  bf16x8 qf[4];

  // QK^T for one 32-key subtile: S^T[key][q], lane holds 16 scores of query lq,
  // key = base + (r&3)+8*(r>>2)+4*hi
  auto qkt = [&](int cur, int sub) -> f32x16 {
    bf16x8 kf[4];
#pragma unroll
    for (int i = 0; i < 4; ++i)
      kf[i] = *(const bf16x8*)&Ks[cur][sub * 4096 + ((lq * 8 + i * 2 + hi) ^ (lq & 7)) * 16];
    f32x16 S = {};
#pragma unroll
    for (int i = 0; i < 4; ++i)
      S = __builtin_amdgcn_mfma_f32_32x32x16_bf16(kf[i], qf[i], S, 0, 0, 0);
    return S;
  };
  auto loadV = [&](int cur, int sub, bf16x8 (&vf)[2][2]) {
#pragma unroll
    for (int d = 0; d < 2; ++d)
#pragma unroll
      for (int ks = 0; ks < 2; ++ks)
        vf[d][ks] = *(const bf16x8*)&Vs[cur][sub * 4096 +
                        ((d * 32 + lq) * 4 + ((ks * 2 + hi) ^ ((lq >> 1) & 3))) * 16];
  };
  // rebuild PV A-fragments from 8 packed words (verified round-2 path)
  auto rebuild = [&](const u32 w[8], bf16x8& o0, bf16x8& o1) {
    u32 sw0 = (u32)__shfl_xor((int)w[0], 32), sw1 = (u32)__shfl_xor((int)w[1], 32);
    u32 sw2 = (u32)__shfl_xor((int)w[2], 32), sw3 = (u32)__shfl_xor((int)w[3], 32);
    u32 sw4 = (u32)__shfl_xor((int)w[4], 32), sw5 = (u32)__shfl_xor((int)w[5], 32);
    u32 sw6 = (u32)__shfl_xor((int)w[6], 32), sw7 = (u32)__shfl_xor((int)w[7], 32);
    union { u32 d[4]; bf16x8 v; } f0, f1;
    f0.d[0] = hi ? sw2 : w[0];
    f0.d[1] = hi ? sw3 : w[1];
    f0.d[2] = hi ? w[2] : sw0;
    f0.d[3] = hi ? w[3] : sw1;
    f1.d[0] = hi ? sw6 : w[4];
    f1.d[1] = hi ? sw7 : w[5];
    f1.d[2] = hi ? w[6] : sw4;
    f1.d[3] = hi ? w[7] : sw5;
    o0 = f0.v;
    o1 = f1.v;
  };

#pragma unroll 1
  for (int rep = 0; rep < 2; ++rep) {
    const int strip = rep ? pairIdx : 63 - pairIdx;
    const int qb = strip * 32;
    const int nt = strip + 1;
    const int nfull = nt >> 1, tail = nt & 1;

    const bf16* qrow = q + (size_t)(b * 2048 + qb + lq) * 1024 + h * 64 + hi * 8;
#pragma unroll
    for (int i = 0; i < 4; ++i) qf[i] = *(const bf16x8*)(qrow + i * 16);

    f32x16 O0 = {}, O1 = {};
    float m = -__builtin_inff(), l = 0.f;

    __syncthreads();  // previous rep's readers done before restaging buffers
    if (nfull) {
      stageK(0, 0, 0); stageK(0, 1, 1);
      stageV(0, 0, 0); stageV(0, 1, 1);
    } else {
      stageK(0, 0, 0); stageV(0, 0, 0);
    }
    __syncthreads();
    int cur = 0;

    for (int r2 = 0; r2 < nfull; ++r2) {
      if (r2 + 1 < nfull) {
        stageK(cur ^ 1, 2 * r2 + 2, 0); stageK(cur ^ 1, 2 * r2 + 3, 1);
        stageV(cur ^ 1, 2 * r2 + 2, 0); stageV(cur ^ 1, 2 * r2 + 3, 1);
      } else if (tail) {
        stageK(cur ^ 1, 2 * nfull, 0); stageV(cur ^ 1, 2 * nfull, 0);
      }

      __builtin_amdgcn_s_setprio(1);
      f32x16 SA = qkt(cur, 0);
      f32x16 SB = qkt(cur, 1);
      __builtin_amdgcn_s_setprio(0);

      if (r2 == nfull - 1 && !tail) {  // subtile B is the diagonal tile
#pragma unroll
        for (int r = 0; r < 16; ++r) {
          int kr = (r & 3) + 8 * (r >> 2) + 4 * hi;
          if (kr > lq) SB[r] = -__builtin_inff();
        }
      }

      // joint row max over 32 scores
      float pm = fmaxf(fmaxf(SA[0], SA[1]), SA[2]);
      pm = fmaxf(fmaxf(pm, SA[3]), SA[4]);
      pm = fmaxf(fmaxf(pm, SA[5]), SA[6]);
      pm = fmaxf(fmaxf(pm, SA[7]), SA[8]);
      pm = fmaxf(fmaxf(pm, SA[9]), SA[10]);
      pm = fmaxf(fmaxf(pm, SA[11]), SA[12]);
      pm = fmaxf(fmaxf(pm, SA[13]), SA[14]);
      pm = fmaxf(fmaxf(pm, SA[15]), SB[0]);
      pm = fmaxf(fmaxf(pm, SB[1]), SB[2]);
      pm = fmaxf(fmaxf(pm, SB[3]), SB[4]);
      pm = fmaxf(fmaxf(pm, SB[5]), SB[6]);
      pm = fmaxf(fmaxf(pm, SB[7]), SB[8]);
      pm = fmaxf(fmaxf(pm, SB[9]), SB[10]);
      pm = fmaxf(fmaxf(pm, SB[11]), SB[12]);
      pm = fmaxf(fmaxf(pm, SB[13]), SB[14]);
      pm = fmaxf(pm, SB[15]);
      pm = fmaxf(pm, __shfl_xor(pm, 32));

      if (!__all(pm <= m + 8.0f)) {  // rescale path (rare after warmup)
        float mn = fmaxf(m, pm);
        float fac = __builtin_amdgcn_exp2f(m - mn);
        m = mn;
        l *= fac;
        if (hi == 0) bc[wid][lq] = fac;
        __threadfence_block();
#pragma unroll
        for (int r = 0; r < 16; ++r) {
          float fr = bc[wid][(r & 3) + 8 * (r >> 2) + 4 * hi];
          O0[r] *= fr;
          O1[r] *= fr;
        }
      }

      float lsA = 0.f, lsB = 0.f;
      u32 wA[8], wB[8];
#pragma unroll
      for (int i = 0; i < 8; ++i) {
        float e0 = __builtin_amdgcn_exp2f(SA[2 * i] - m);
        float e1 = __builtin_amdgcn_exp2f(SA[2 * i + 1] - m);
        lsA += e0 + e1;
        wA[i] = pack2(e0, e1);
      }
#pragma unroll
      for (int i = 0; i < 8; ++i) {
        float e0 = __builtin_amdgcn_exp2f(SB[2 * i] - m);
        float e1 = __builtin_amdgcn_exp2f(SB[2 * i + 1] - m);
        lsB += e0 + e1;
        wB[i] = pack2(e0, e1);
      }
      float ls = lsA + lsB;
      ls += __shfl_xor(ls, 32);
      l += ls;

      bf16x8 f0A, f1A, f0B, f1B;
      rebuild(wA, f0A, f1A);
      rebuild(wB, f0B, f1B);

      bf16x8 vfA[2][2], vfB[2][2];
      loadV(cur, 0, vfA);
      loadV(cur, 1, vfB);

      __builtin_amdgcn_s_setprio(1);
      O0 = __builtin_amdgcn_mfma_f32_32x32x16_bf16(f0A, vfA[0][0], O0, 0, 0, 0);
      O0 = __builtin_amdgcn_mfma_f32_32x32x16_bf16(f1A, vfA[0][1], O0, 0, 0, 0);
      O0 = __builtin_amdgcn_mfma_f32_32x32x16_bf16(f0B, vfB[0][0], O0, 0, 0, 0);
      O0 = __builtin_amdgcn_mfma_f32_32x32x16_bf16(f1B, vfB[0][1], O0, 0, 0, 0);
      O1 = __builtin_amdgcn_mfma_f32_32x32x16_bf16(f0A, vfA[1][0], O1, 0, 0, 0);
      O1 = __builtin_amdgcn_mfma_f32_32x32x16_bf16(f1A, vfA[1][1], O1, 0, 0, 0);
      O1 = __builtin_amdgcn_mfma_f32_32x32x16_bf16(f0B, vfB[1][0], O1, 0, 0, 0);
      O1 = __builtin_amdgcn_mfma_f32_32x32x16_bf16(f1B, vfB[1][1], O1, 0, 0, 0);
      __builtin_amdgcn_s_setprio(0);

      __syncthreads();  // own staging drained + all waves done reading
      cur ^= 1;
    }

    if (tail) {  // final 32-key diagonal tile (nt odd), staged in buffer `cur` sub 0
      __builtin_amdgcn_s_setprio(1);
      f32x16 S = qkt(cur, 0);
      __builtin_amdgcn_s_setprio(0);
#pragma unroll
      for (int r = 0; r < 16; ++r) {
        int kr = (r & 3) + 8 * (r >> 2) + 4 * hi;
        if (kr > lq) S[r] = -__builtin_inff();
      }
      float pm = fmaxf(fmaxf(S[0], S[1]), S[2]);
      pm = fmaxf(fmaxf(pm, S[3]), S[4]);
      pm = fmaxf(fmaxf(pm, S[5]), S[6]);
      pm = fmaxf(fmaxf(pm, S[7]), S[8]);
      pm = fmaxf(fmaxf(pm, S[9]), S[10]);
      pm = fmaxf(fmaxf(pm, S[11]), S[12]);
      pm = fmaxf(fmaxf(pm, S[13]), S[14]);
      pm = fmaxf(pm, S[15]);
      pm = fmaxf(pm, __shfl_xor(pm, 32));

      if (!__all(pm <= m + 8.0f)) {
        float mn = fmaxf(m, pm);
        float fac = __builtin_amdgcn_exp2f(m - mn);
        m = mn;
        l *= fac;
        if (hi == 0) bc[wid][lq] = fac;
        __threadfence_block();
#pragma unroll
        for (int r = 0; r < 16; ++r) {
          float fr = bc[wid][(r & 3) + 8 * (r >> 2) + 4 * hi];
          O0[r] *= fr;
          O1[r] *= fr;
        }
      }

      float ls = 0.f;
      u32 w[8];
#pragma unroll
      for (int i = 0; i < 8; ++i) {
        float e0 = __builtin_amdgcn_exp2f(S[2 * i] - m);
        float e1 = __builtin_amdgcn_exp2f(S[2 * i + 1] - m);
        ls += e0 + e1;
        w[i] = pack2(e0, e1);
      }
      ls += __shfl_xor(ls, 32);
      l += ls;

      bf16x8 f0, f1;
      rebuild(w, f0, f1);
      bf16x8 vf[2][2];
      loadV(cur, 0, vf);

      __builtin_amdgcn_s_setprio(1);
      O0 = __builtin_amdgcn_mfma_f32_32x32x16_bf16(f0, vf[0][0], O0, 0, 0, 0);
      O0 = __builtin_amdgcn_mfma_f32_32x32x16_bf16(f1, vf[0][1], O0, 0, 0, 0);
      O1 = __builtin_amdgcn_mfma_f32_32x32x16_bf16(f0, vf[1][0], O1, 0, 0, 0);
      O1 = __builtin_amdgcn_mfma_f32_32x32x16_bf16(f1, vf[1][1], O1, 0, 0, 0);
      __builtin_amdgcn_s_setprio(0);
    }

    // epilogue: normalize by 1/l (broadcast per output row) and store
    float linv = 1.0f / l;
    if (hi == 0) bc[wid][lq] = linv;
    __threadfence_block();
#pragma unroll
    for (int r = 0; r < 16; ++r) {
      int row = (r & 3) + 8 * (r >> 2) + 4 * hi;
      float sc = bc[wid][row];
      size_t base = (size_t)(b * 2048 + qb + row) * 1024 + h * 64;
      o[base + lq] = (bf16)(O0[r] * sc);
      o[base + 32 + lq] = (bf16)(O1[r] * sc);
    }
  }
}

// ---------------- launch ----------------
extern "C" void kernel_launch(void* const* d_in, const int* in_sizes, int n_in,
                              void* d_out, int out_size, void* d_ws, size_t ws_size,
                              hipStream_t stream) {
  const float* Q  = (const float*)d_in[0];
  const float* K  = (const float*)d_in[1];
  const float* V  = (const float*)d_in[2];
  const float* wq = (const float*)d_in[3];
  const float* wk = (const float*)d_in[4];
  const float* wv = (const float*)d_in[5];
  const float* wo = (const float*)d_in[6];
  float* out = (float*)d_out;

  char* ws = (char*)d_ws;
  bf16* qp   = (bf16*)(ws + (48ull << 20));          // q proj bf16, 16 MB
  bf16* ab   = (bf16*)(ws + (64ull << 20));          // attn out bf16, 16 MB
  bf16* kp   = (bf16*)(ws + (80ull << 20));          // [b][key][64], 1 MB
  bf16* vTp  = (bf16*)(ws + (81ull << 20));          // [b][tile][d][key32], 1 MB
  bf16* wqT  = (bf16*)(ws + (82ull << 20));          // 2 MB
  bf16* woT  = (bf16*)(ws + (84ull << 20));          // 2 MB
  bf16* wkvT = (bf16*)(ws + (86ull << 20));          // [128][1024] = 256 KB

  // fold softmax scale (1/sqrt(64)) and log2(e) into Wq (exp2-based softmax)
  const float SCALE = 0.125f * 1.44269504088896340736f;
  transpose_all<<<dim3(68, 32), 256, 0, stream>>>(wq, wk, wv, wo, wqT, wkvT, woT, SCALE);

  proj_kernel<<<640, 256, 0, stream>>>(Q, K, V, wqT, wkvT, qp, kp, vTp);

  attn_kernel<<<dim3(32, 4, 4), 256, 0, stream>>>(qp, kp, vTp, ab);

  gemm_bt<float><<<dim3(64, 8), 256, 0, stream>>>(ab, woT, out, 8192, 1024, 1024);
}

// Round 16
// 151.113 us; speedup vs baseline: 1.2925x; 1.0174x over previous
//
#include <hip/hip_runtime.h>

typedef __bf16 bf16;
typedef unsigned int u32;
typedef __bf16 bf16x8 __attribute__((ext_vector_type(8)));
typedef float f32x4 __attribute__((ext_vector_type(4)));
typedef float f32x16 __attribute__((ext_vector_type(16)));

#define DEV __device__ __forceinline__

// async global->LDS, 16B per lane; lds base must be wave-uniform (HW adds lane*16);
// global source address IS per-lane (m173)
DEV void gload_lds16(const void* g, void* l) {
  __builtin_amdgcn_global_load_lds((const __attribute__((address_space(1))) void*)g,
                                   (__attribute__((address_space(3))) void*)l,
                                   16, 0, 0);
}

DEV u32 pack2(float a, float b) {
  unsigned short ua = __builtin_bit_cast(unsigned short, (bf16)a);
  unsigned short ub = __builtin_bit_cast(unsigned short, (bf16)b);
  return (u32)ua | ((u32)ub << 16);
}

// ---------------- all weight transposes in ONE launch ----------------
__global__ void transpose_all(const float* __restrict__ wq, const float* __restrict__ wk,
                              const float* __restrict__ wv, const float* __restrict__ wo,
                              bf16* __restrict__ wqT, bf16* __restrict__ wkvT,
                              bf16* __restrict__ woT, float scale_q) {
  __shared__ float tile[32][33];
  int x = blockIdx.x;
  const float* in;
  bf16* out;
  int C;
  float scale = 1.0f;
  int c0;
  if (x < 32)      { in = wq; out = wqT;             C = 1024; c0 = x * 32; scale = scale_q; }
  else if (x < 34) { in = wk; out = wkvT;            C = 64;   c0 = (x - 32) * 32; }
  else if (x < 36) { in = wv; out = wkvT + 64 * 1024; C = 64;  c0 = (x - 34) * 32; }
  else             { in = wo; out = woT;             C = 1024; c0 = (x - 36) * 32; }
  int r0 = blockIdx.y * 32;
  int tx = threadIdx.x & 31, ty = threadIdx.x >> 5;  // 256 threads = 32x8
  for (int i = ty; i < 32; i += 8) tile[i][tx] = in[(size_t)(r0 + i) * C + c0 + tx];
  __syncthreads();
  for (int i = ty; i < 32; i += 8)
    out[(size_t)(c0 + i) * 1024 + r0 + tx] = (bf16)(tile[tx][i] * scale);
}

// ---------------- bf16 GEMM, B transposed (Bt[N][K]), 2-phase ----------------
template <typename OutT>
__global__ __launch_bounds__(256)
void gemm_bt(const bf16* __restrict__ A, const bf16* __restrict__ Bt,
             OutT* __restrict__ C, int M, int N, int K) {
  __shared__ __align__(16) bf16 As[2][128 * 32];
  __shared__ __align__(16) bf16 Bs[2][128 * 32];
  const int tid = threadIdx.x;
  const int wid = tid >> 6, lane = tid & 63;
  const int wr = wid >> 1, wc = wid & 1;
  const int lx = lane & 15, g = lane >> 4;
  const size_t bm = (size_t)blockIdx.x * 128;
  const size_t bn = (size_t)blockIdx.y * 128;
  f32x4 acc[4][4] = {};
  const int nk = K >> 5;

  auto stage = [&](int buf, int k0) {
#pragma unroll
    for (int i = 0; i < 2; ++i) {
      int c = i * 256 + wid * 64 + lane;
      const bf16* gp = A + (bm + (size_t)(c >> 2)) * K + k0 + (c & 3) * 8;
      gload_lds16(gp, (char*)As[buf] + (size_t)(i * 256 + wid * 64) * 16);
    }
#pragma unroll
    for (int i = 0; i < 2; ++i) {
      int c = i * 256 + wid * 64 + lane;
      const bf16* gp = Bt + (bn + (size_t)(c >> 2)) * K + k0 + (c & 3) * 8;
      gload_lds16(gp, (char*)Bs[buf] + (size_t)(i * 256 + wid * 64) * 16);
    }
  };

  stage(0, 0);
  __syncthreads();
  int cur = 0;

  for (int t = 0; t < nk; ++t) {
    if (t + 1 < nk) stage(cur ^ 1, (t + 1) * 32);

    bf16x8 af[4], bfr[4];
#pragma unroll
    for (int m = 0; m < 4; ++m)
      af[m] = *(const bf16x8*)&As[cur][(wr * 64 + m * 16 + lx) * 32 + g * 8];
#pragma unroll
    for (int n = 0; n < 4; ++n)
      bfr[n] = *(const bf16x8*)&Bs[cur][(wc * 64 + n * 16 + lx) * 32 + g * 8];
#pragma unroll
    for (int m = 0; m < 4; ++m)
#pragma unroll
      for (int n = 0; n < 4; ++n)
        acc[m][n] = __builtin_amdgcn_mfma_f32_16x16x32_bf16(af[m], bfr[n], acc[m][n], 0, 0, 0);

    __syncthreads();  // drains t+1 staging (after compute) + readers done with cur
    cur ^= 1;
  }

#pragma unroll
  for (int m = 0; m < 4; ++m)
#pragma unroll
    for (int n = 0; n < 4; ++n) {
      size_t row = bm + wr * 64 + m * 16 + g * 4;
      size_t col = bn + wc * 64 + n * 16 + lx;
#pragma unroll
      for (int j = 0; j < 4; ++j)
        C[(row + j) * N + col] = (OutT)acc[m][n][j];
    }
}

// ---------------- fused cast+projections: q = Q@wq ; [k|v] = [K;V]@[wk|wv] --------
// 2-phase + T14 split on the reg-staged A path.
__global__ __launch_bounds__(256)
void proj_kernel(const float* __restrict__ Qf, const float* __restrict__ Kf,
                 const float* __restrict__ Vf, const bf16* __restrict__ wqT,
                 const bf16* __restrict__ wkvT, bf16* __restrict__ qp,
                 bf16* __restrict__ kp, bf16* __restrict__ vTp) {
  const int bid = blockIdx.x;
  const bool isq = bid < 512;
  const float* Af;
  size_t arow, bm, bn;
  const bf16* Bt = isq ? wqT : wkvT;
  if (isq) {
    bm = (size_t)(bid & 63) * 128;
    arow = bm;
    bn = (size_t)(bid >> 6) * 128;
    Af = Qf;
  } else {
    int kv = bid - 512;  // 0..127 rows of stacked [K;V]
    bm = (size_t)kv * 128;
    bn = 0;
    if (kv < 64) { Af = Kf; arow = bm; } else { Af = Vf; arow = bm - 8192; }
  }

  __shared__ __align__(16) bf16 As[2][128 * 32];
  __shared__ __align__(16) bf16 Bs[2][128 * 32];
  const int tid = threadIdx.x;
  const int wid = tid >> 6, lane = tid & 63;
  const int wr = wid >> 1, wc = wid & 1;
  const int lx = lane & 15, g = lane >> 4;
  f32x4 acc[4][4] = {};

  auto loadA = [&](int k0, float4 (&ar)[2][2]) {
#pragma unroll
    for (int i = 0; i < 2; ++i) {
      int c = i * 256 + tid;
      const float* src = Af + (arow + (size_t)(c >> 2)) * 1024 + k0 + (c & 3) * 8;
      ar[i][0] = *(const float4*)src;
      ar[i][1] = *(const float4*)(src + 4);
    }
  };
  auto writeA = [&](int buf, const float4 (&ar)[2][2]) {
#pragma unroll
    for (int i = 0; i < 2; ++i) {
      bf16x8 v;
      v[0] = (bf16)ar[i][0].x; v[1] = (bf16)ar[i][0].y;
      v[2] = (bf16)ar[i][0].z; v[3] = (bf16)ar[i][0].w;
      v[4] = (bf16)ar[i][1].x; v[5] = (bf16)ar[i][1].y;
      v[6] = (bf16)ar[i][1].z; v[7] = (bf16)ar[i][1].w;
      *(bf16x8*)((char*)As[buf] + (size_t)(i * 256 + tid) * 16) = v;
    }
  };
  auto stageB = [&](int buf, int k0) {
#pragma unroll
    for (int i = 0; i < 2; ++i) {
      int c = i * 256 + wid * 64 + lane;
      const bf16* gp = Bt + (bn + (size_t)(c >> 2)) * 1024 + k0 + (c & 3) * 8;
      gload_lds16(gp, (char*)Bs[buf] + (size_t)(i * 256 + wid * 64) * 16);
    }
  };

  // prologue: tile 0
  {
    float4 ar[2][2];
    loadA(0, ar);
    stageB(0, 0);
    writeA(0, ar);
  }
  __syncthreads();
  int cur = 0;

  for (int t = 0; t < 32; ++t) {
    float4 ar[2][2];
    const bool more = t + 1 < 32;
    if (more) {
      loadA((t + 1) * 32, ar);   // issue fp32 loads early (T14)
      stageB(cur ^ 1, (t + 1) * 32);
    }

    bf16x8 af[4], bfr[4];
#pragma unroll
    for (int m = 0; m < 4; ++m)
      af[m] = *(const bf16x8*)&As[cur][(wr * 64 + m * 16 + lx) * 32 + g * 8];
#pragma unroll
    for (int n = 0; n < 4; ++n)
      bfr[n] = *(const bf16x8*)&Bs[cur][(wc * 64 + n * 16 + lx) * 32 + g * 8];
#pragma unroll
    for (int m = 0; m < 4; ++m)
#pragma unroll
      for (int n = 0; n < 4; ++n)
        acc[m][n] = __builtin_amdgcn_mfma_f32_16x16x32_bf16(af[m], bfr[n], acc[m][n], 0, 0, 0);

    if (more) writeA(cur ^ 1, ar);  // vmcnt wait + convert AFTER compute

    __syncthreads();  // drains B staging + A writes; readers done with cur
    cur ^= 1;
  }

#pragma unroll
  for (int m = 0; m < 4; ++m)
#pragma unroll
    for (int n = 0; n < 4; ++n) {
      size_t row = bm + wr * 64 + m * 16 + g * 4;
      size_t col = bn + wc * 64 + n * 16 + lx;
#pragma unroll
      for (int j = 0; j < 4; ++j) {
        float v = acc[m][n][j];
        size_t r = row + j;
        if (isq) {
          qp[r * 1024 + col] = (bf16)v;
        } else if (col < 64) {
          if (r < 8192) kp[r * 64 + col] = (bf16)v;  // [b*2048+key][64]
        } else {
          if (r >= 8192) {
            size_t rr = r - 8192;
            size_t bb = rr >> 11, nn = rr & 2047;
            vTp[bb * 131072 + (nn >> 5) * 2048 + (col - 64) * 32 + (nn & 31)] = (bf16)v;
          }
        }
      }
    }
}

// ---------------- causal multi-query flash attention (round-8 config + r16 ILP) ----
// grid (32 strip-pairs, 4 head-groups, 4 batch) = 512 blocks, 4 waves = 4 HEADS.
// ROUND 16 latency trims on the verified body (no sync-structure change):
//  (1) joint row-max as 4 INDEPENDENT 8-value chains + depth-2 combine (was a
//      31-deep serial fmax chain -- ~4x shorter critical path);
//  (2) loadV hoisted BEFORE the softmax (ds_read latency hides under exp2/pack;
//      +16 VGPR, still under the 128 two-block cap).
__global__ __launch_bounds__(256, 2)
void attn_kernel(const bf16* __restrict__ q, const bf16* __restrict__ k,
                 const bf16* __restrict__ vt, bf16* __restrict__ o) {
  const int hg = blockIdx.y, b = blockIdx.z;
  const int wid = threadIdx.x >> 6, lane = threadIdx.x & 63;
  const int lq = lane & 31, hi = lane >> 5;
  const int h = hg * 4 + wid;
  const int pairIdx = blockIdx.x;  // 0..31

  __shared__ __align__(16) char Ks[2][8192];  // 2 x 4KB subtiles (32 keys x 64d each)
  __shared__ __align__(16) char Vs[2][8192];  // 2 x 4KB subtiles (64d x 32 keys each)
  __shared__ float bc[4][32];

  const bf16* kb = k + (size_t)b * 2048 * 64;                // [key][64]
  const char* vbase = (const char*)vt + (size_t)b * 262144;  // [tile][d][key32]

  // stage one 4KB K tile kt into buffer bi, subtile sub (swizzle at SOURCE, rule 21)
  auto stageK = [&](int bi, int kt, int sub) {
    int src = (wid * 64 + lane) ^ ((lane >> 3) & 7);
    gload_lds16((const char*)(kb + (size_t)kt * 2048) + src * 16,
                &Ks[bi][sub * 4096 + wid * 1024]);
  };
  auto stageV = [&](int bi, int kt, int sub) {
    int g = wid * 64 + lane;
    int src = (g & ~3) | ((g & 3) ^ ((lane >> 3) & 3));
    gload_lds16(vbase + (size_t)kt * 4096 + src * 16, &Vs[bi][sub * 4096 + wid * 1024]);
  };

  bf16x8 qf[4];

  // QK^T for one 32-key subtile: S^T[key][q], lane holds 16 scores of query lq,
  // key = base + (r&3)+8*(r>>2)+4*hi
  auto qkt = [&](int cur, int sub) -> f32x16 {
    bf16x8 kf[4];
#pragma unroll
    for (int i = 0; i < 4; ++i)
      kf[i] = *(const bf16x8*)&Ks[cur][sub * 4096 + ((lq * 8 + i * 2 + hi) ^ (lq & 7)) * 16];
    f32x16 S = {};
#pragma unroll
    for (int i = 0; i < 4; ++i)
      S = __builtin_amdgcn_mfma_f32_32x32x16_bf16(kf[i], qf[i], S, 0, 0, 0);
    return S;
  };
  auto loadV = [&](int cur, int sub, bf16x8 (&vf)[2][2]) {
#pragma unroll
    for (int d = 0; d < 2; ++d)
#pragma unroll
      for (int ks = 0; ks < 2; ++ks)
        vf[d][ks] = *(const bf16x8*)&Vs[cur][sub * 4096 +
                        ((d * 32 + lq) * 4 + ((ks * 2 + hi) ^ ((lq >> 1) & 3))) * 16];
  };
  // 16-value max as two independent 8-chains (ILP 2, max3-fusable triples)
  auto vmax16 = [&](const f32x16& S) -> float {
    float a = fmaxf(fmaxf(S[0], S[1]), S[2]);
    a = fmaxf(fmaxf(a, S[3]), S[4]);
    a = fmaxf(fmaxf(a, S[5]), S[6]);
    a = fmaxf(a, S[7]);
    float c = fmaxf(fmaxf(S[8], S[9]), S[10]);
    c = fmaxf(fmaxf(c, S[11]), S[12]);
    c = fmaxf(fmaxf(c, S[13]), S[14]);
    c = fmaxf(c, S[15]);
    return fmaxf(a, c);
  };
  // rebuild PV A-fragments from 8 packed words (verified round-2 path)
  auto rebuild = [&](const u32 w[8], bf16x8& o0, bf16x8& o1) {
    u32 sw0 = (u32)__shfl_xor((int)w[0], 32), sw1 = (u32)__shfl_xor((int)w[1], 32);
    u32 sw2 = (u32)__shfl_xor((int)w[2], 32), sw3 = (u32)__shfl_xor((int)w[3], 32);
    u32 sw4 = (u32)__shfl_xor((int)w[4], 32), sw5 = (u32)__shfl_xor((int)w[5], 32);
    u32 sw6 = (u32)__shfl_xor((int)w[6], 32), sw7 = (u32)__shfl_xor((int)w[7], 32);
    union { u32 d[4]; bf16x8 v; } f0, f1;
    f0.d[0] = hi ? sw2 : w[0];
    f0.d[1] = hi ? sw3 : w[1];
    f0.d[2] = hi ? w[2] : sw0;
    f0.d[3] = hi ? w[3] : sw1;
    f1.d[0] = hi ? sw6 : w[4];
    f1.d[1] = hi ? sw7 : w[5];
    f1.d[2] = hi ? w[6] : sw4;
    f1.d[3] = hi ? w[7] : sw5;
    o0 = f0.v;
    o1 = f1.v;
  };

#pragma unroll 1
  for (int rep = 0; rep < 2; ++rep) {
    const int strip = rep ? pairIdx : 63 - pairIdx;
    const int qb = strip * 32;
    const int nt = strip + 1;
    const int nfull = nt >> 1, tail = nt & 1;

    const bf16* qrow = q + (size_t)(b * 2048 + qb + lq) * 1024 + h * 64 + hi * 8;
#pragma unroll
    for (int i = 0; i < 4; ++i) qf[i] = *(const bf16x8*)(qrow + i * 16);

    f32x16 O0 = {}, O1 = {};
    float m = -__builtin_inff(), l = 0.f;

    __syncthreads();  // previous rep's readers done before restaging buffers
    if (nfull) {
      stageK(0, 0, 0); stageK(0, 1, 1);
      stageV(0, 0, 0); stageV(0, 1, 1);
    } else {
      stageK(0, 0, 0); stageV(0, 0, 0);
    }
    __syncthreads();
    int cur = 0;

    for (int r2 = 0; r2 < nfull; ++r2) {
      if (r2 + 1 < nfull) {
        stageK(cur ^ 1, 2 * r2 + 2, 0); stageK(cur ^ 1, 2 * r2 + 3, 1);
        stageV(cur ^ 1, 2 * r2 + 2, 0); stageV(cur ^ 1, 2 * r2 + 3, 1);
      } else if (tail) {
        stageK(cur ^ 1, 2 * nfull, 0); stageV(cur ^ 1, 2 * nfull, 0);
      }

      __builtin_amdgcn_s_setprio(1);
      f32x16 SA = qkt(cur, 0);
      f32x16 SB = qkt(cur, 1);
      __builtin_amdgcn_s_setprio(0);

      // hoist V reads: ds_read latency hides under the softmax VALU below
      bf16x8 vfA[2][2], vfB[2][2];
      loadV(cur, 0, vfA);
      loadV(cur, 1, vfB);

      if (r2 == nfull - 1 && !tail) {  // subtile B is the diagonal tile
#pragma unroll
        for (int r = 0; r < 16; ++r) {
          int kr = (r & 3) + 8 * (r >> 2) + 4 * hi;
          if (kr > lq) SB[r] = -__builtin_inff();
        }
      }

      // joint row max: 4 independent 8-chains (via 2x vmax16), depth-2 combine
      float pmA = vmax16(SA);
      float pmB = vmax16(SB);
      float pm = fmaxf(pmA, pmB);
      pm = fmaxf(pm, __shfl_xor(pm, 32));

      if (!__all(pm <= m + 8.0f)) {  // rescale path (rare after warmup)
        float mn = fmaxf(m, pm);
        float fac = __builtin_amdgcn_exp2f(m - mn);
        m = mn;
        l *= fac;
        if (hi == 0) bc[wid][lq] = fac;
        __threadfence_block();
#pragma unroll
        for (int r = 0; r < 16; ++r) {
          float fr = bc[wid][(r & 3) + 8 * (r >> 2) + 4 * hi];
          O0[r] *= fr;
          O1[r] *= fr;
        }
      }

      float lsA = 0.f, lsB = 0.f;
      u32 wA[8], wB[8];
#pragma unroll
      for (int i = 0; i < 8; ++i) {
        float e0 = __builtin_amdgcn_exp2f(SA[2 * i] - m);
        float e1 = __builtin_amdgcn_exp2f(SA[2 * i + 1] - m);
        lsA += e0 + e1;
        wA[i] = pack2(e0, e1);
      }
#pragma unroll
      for (int i = 0; i < 8; ++i) {
        float e0 = __builtin_amdgcn_exp2f(SB[2 * i] - m);
        float e1 = __builtin_amdgcn_exp2f(SB[2 * i + 1] - m);
        lsB += e0 + e1;
        wB[i] = pack2(e0, e1);
      }
      float ls = lsA + lsB;
      ls += __shfl_xor(ls, 32);
      l += ls;

      bf16x8 f0A, f1A, f0B, f1B;
      rebuild(wA, f0A, f1A);
      rebuild(wB, f0B, f1B);

      __builtin_amdgcn_s_setprio(1);
      O0 = __builtin_amdgcn_mfma_f32_32x32x16_bf16(f0A, vfA[0][0], O0, 0, 0, 0);
      O0 = __builtin_amdgcn_mfma_f32_32x32x16_bf16(f1A, vfA[0][1], O0, 0, 0, 0);
      O0 = __builtin_amdgcn_mfma_f32_32x32x16_bf16(f0B, vfB[0][0], O0, 0, 0, 0);
      O0 = __builtin_amdgcn_mfma_f32_32x32x16_bf16(f1B, vfB[0][1], O0, 0, 0, 0);
      O1 = __builtin_amdgcn_mfma_f32_32x32x16_bf16(f0A, vfA[1][0], O1, 0, 0, 0);
      O1 = __builtin_amdgcn_mfma_f32_32x32x16_bf16(f1A, vfA[1][1], O1, 0, 0, 0);
      O1 = __builtin_amdgcn_mfma_f32_32x32x16_bf16(f0B, vfB[1][0], O1, 0, 0, 0);
      O1 = __builtin_amdgcn_mfma_f32_32x32x16_bf16(f1B, vfB[1][1], O1, 0, 0, 0);
      __builtin_amdgcn_s_setprio(0);

      __syncthreads();  // own staging drained + all waves done reading
      cur ^= 1;
    }

    if (tail) {  // final 32-key diagonal tile (nt odd), staged in buffer `cur` sub 0
      __builtin_amdgcn_s_setprio(1);
      f32x16 S = qkt(cur, 0);
      __builtin_amdgcn_s_setprio(0);
      bf16x8 vf[2][2];
      loadV(cur, 0, vf);
#pragma unroll
      for (int r = 0; r < 16; ++r) {
        int kr = (r & 3) + 8 * (r >> 2) + 4 * hi;
        if (kr > lq) S[r] = -__builtin_inff();
      }
      float pm = vmax16(S);
      pm = fmaxf(pm, __shfl_xor(pm, 32));

      if (!__all(pm <= m + 8.0f)) {
        float mn = fmaxf(m, pm);
        float fac = __builtin_amdgcn_exp2f(m - mn);
        m = mn;
        l *= fac;
        if (hi == 0) bc[wid][lq] = fac;
        __threadfence_block();
#pragma unroll
        for (int r = 0; r < 16; ++r) {
          float fr = bc[wid][(r & 3) + 8 * (r >> 2) + 4 * hi];
          O0[r] *= fr;
          O1[r] *= fr;
        }
      }

      float ls = 0.f;
      u32 w[8];
#pragma unroll
      for (int i = 0; i < 8; ++i) {
        float e0 = __builtin_amdgcn_exp2f(S[2 * i] - m);
        float e1 = __builtin_amdgcn_exp2f(S[2 * i + 1] - m);
        ls += e0 + e1;
        w[i] = pack2(e0, e1);
      }
      ls += __shfl_xor(ls, 32);
      l += ls;

      bf16x8 f0, f1;
      rebuild(w, f0, f1);

      __builtin_amdgcn_s_setprio(1);
      O0 = __builtin_amdgcn_mfma_f32_32x32x16_bf16(f0, vf[0][0], O0, 0, 0, 0);
      O0 = __builtin_amdgcn_mfma_f32_32x32x16_bf16(f1, vf[0][1], O0, 0, 0, 0);
      O1 = __builtin_amdgcn_mfma_f32_32x32x16_bf16(f0, vf[1][0], O1, 0, 0, 0);
      O1 = __builtin_amdgcn_mfma_f32_32x32x16_bf16(f1, vf[1][1], O1, 0, 0, 0);
      __builtin_amdgcn_s_setprio(0);
    }

    // epilogue: normalize by 1/l (broadcast per output row) and store
    float linv = 1.0f / l;
    if (hi == 0) bc[wid][lq] = linv;
    __threadfence_block();
#pragma unroll
    for (int r = 0; r < 16; ++r) {
      int row = (r & 3) + 8 * (r >> 2) + 4 * hi;
      float sc = bc[wid][row];
      size_t base = (size_t)(b * 2048 + qb + row) * 1024 + h * 64;
      o[base + lq] = (bf16)(O0[r] * sc);
      o[base + 32 + lq] = (bf16)(O1[r] * sc);
    }
  }
}

// ---------------- launch ----------------
extern "C" void kernel_launch(void* const* d_in, const int* in_sizes, int n_in,
                              void* d_out, int out_size, void* d_ws, size_t ws_size,
                              hipStream_t stream) {
  const float* Q  = (const float*)d_in[0];
  const float* K  = (const float*)d_in[1];
  const float* V  = (const float*)d_in[2];
  const float* wq = (const float*)d_in[3];
  const float* wk = (const float*)d_in[4];
  const float* wv = (const float*)d_in[5];
  const float* wo = (const float*)d_in[6];
  float* out = (float*)d_out;

  char* ws = (char*)d_ws;
  bf16* qp   = (bf16*)(ws + (48ull << 20));          // q proj bf16, 16 MB
  bf16* ab   = (bf16*)(ws + (64ull << 20));          // attn out bf16, 16 MB
  bf16* kp   = (bf16*)(ws + (80ull << 20));          // [b][key][64], 1 MB
  bf16* vTp  = (bf16*)(ws + (81ull << 20));          // [b][tile][d][key32], 1 MB
  bf16* wqT  = (bf16*)(ws + (82ull << 20));          // 2 MB
  bf16* woT  = (bf16*)(ws + (84ull << 20));          // 2 MB
  bf16* wkvT = (bf16*)(ws + (86ull << 20));          // [128][1024] = 256 KB

  // fold softmax scale (1/sqrt(64)) and log2(e) into Wq (exp2-based softmax)
  const float SCALE = 0.125f * 1.44269504088896340736f;
  transpose_all<<<dim3(68, 32), 256, 0, stream>>>(wq, wk, wv, wo, wqT, wkvT, woT, SCALE);

  proj_kernel<<<640, 256, 0, stream>>>(Q, K, V, wqT, wkvT, qp, kp, vTp);

  attn_kernel<<<dim3(32, 4, 4), 256, 0, stream>>>(qp, kp, vTp, ab);

  gemm_bt<float><<<dim3(64, 8), 256, 0, stream>>>(ab, woT, out, 8192, 1024, 1024);
}

// Round 17
// 150.318 us; speedup vs baseline: 1.2993x; 1.0053x over previous
//
#include <hip/hip_runtime.h>

typedef __bf16 bf16;
typedef unsigned int u32;
typedef __bf16 bf16x8 __attribute__((ext_vector_type(8)));
typedef float f32x4 __attribute__((ext_vector_type(4)));
typedef float f32x16 __attribute__((ext_vector_type(16)));

#define DEV __device__ __forceinline__

// async global->LDS, 16B per lane; lds base must be wave-uniform (HW adds lane*16);
// global source address IS per-lane (m173)
DEV void gload_lds16(const void* g, void* l) {
  __builtin_amdgcn_global_load_lds((const __attribute__((address_space(1))) void*)g,
                                   (__attribute__((address_space(3))) void*)l,
                                   16, 0, 0);
}

DEV u32 pack2(float a, float b) {
  unsigned short ua = __builtin_bit_cast(unsigned short, (bf16)a);
  unsigned short ub = __builtin_bit_cast(unsigned short, (bf16)b);
  return (u32)ua | ((u32)ub << 16);
}

// ---------------- all weight transposes in ONE launch ----------------
__global__ void transpose_all(const float* __restrict__ wq, const float* __restrict__ wk,
                              const float* __restrict__ wv, const float* __restrict__ wo,
                              bf16* __restrict__ wqT, bf16* __restrict__ wkvT,
                              bf16* __restrict__ woT, float scale_q) {
  __shared__ float tile[32][33];
  int x = blockIdx.x;
  const float* in;
  bf16* out;
  int C;
  float scale = 1.0f;
  int c0;
  if (x < 32)      { in = wq; out = wqT;             C = 1024; c0 = x * 32; scale = scale_q; }
  else if (x < 34) { in = wk; out = wkvT;            C = 64;   c0 = (x - 32) * 32; }
  else if (x < 36) { in = wv; out = wkvT + 64 * 1024; C = 64;  c0 = (x - 34) * 32; }
  else             { in = wo; out = woT;             C = 1024; c0 = (x - 36) * 32; }
  int r0 = blockIdx.y * 32;
  int tx = threadIdx.x & 31, ty = threadIdx.x >> 5;  // 256 threads = 32x8
  for (int i = ty; i < 32; i += 8) tile[i][tx] = in[(size_t)(r0 + i) * C + c0 + tx];
  __syncthreads();
  for (int i = ty; i < 32; i += 8)
    out[(size_t)(c0 + i) * 1024 + r0 + tx] = (bf16)(tile[tx][i] * scale);
}

// ---------------- bf16 GEMM, B transposed (Bt[N][K]), 2-phase ----------------
template <typename OutT>
__global__ __launch_bounds__(256)
void gemm_bt(const bf16* __restrict__ A, const bf16* __restrict__ Bt,
             OutT* __restrict__ C, int M, int N, int K) {
  __shared__ __align__(16) bf16 As[2][128 * 32];
  __shared__ __align__(16) bf16 Bs[2][128 * 32];
  const int tid = threadIdx.x;
  const int wid = tid >> 6, lane = tid & 63;
  const int wr = wid >> 1, wc = wid & 1;
  const int lx = lane & 15, g = lane >> 4;
  const size_t bm = (size_t)blockIdx.x * 128;
  const size_t bn = (size_t)blockIdx.y * 128;
  f32x4 acc[4][4] = {};
  const int nk = K >> 5;

  auto stage = [&](int buf, int k0) {
#pragma unroll
    for (int i = 0; i < 2; ++i) {
      int c = i * 256 + wid * 64 + lane;
      const bf16* gp = A + (bm + (size_t)(c >> 2)) * K + k0 + (c & 3) * 8;
      gload_lds16(gp, (char*)As[buf] + (size_t)(i * 256 + wid * 64) * 16);
    }
#pragma unroll
    for (int i = 0; i < 2; ++i) {
      int c = i * 256 + wid * 64 + lane;
      const bf16* gp = Bt + (bn + (size_t)(c >> 2)) * K + k0 + (c & 3) * 8;
      gload_lds16(gp, (char*)Bs[buf] + (size_t)(i * 256 + wid * 64) * 16);
    }
  };

  stage(0, 0);
  __syncthreads();
  int cur = 0;

  for (int t = 0; t < nk; ++t) {
    if (t + 1 < nk) stage(cur ^ 1, (t + 1) * 32);

    bf16x8 af[4], bfr[4];
#pragma unroll
    for (int m = 0; m < 4; ++m)
      af[m] = *(const bf16x8*)&As[cur][(wr * 64 + m * 16 + lx) * 32 + g * 8];
#pragma unroll
    for (int n = 0; n < 4; ++n)
      bfr[n] = *(const bf16x8*)&Bs[cur][(wc * 64 + n * 16 + lx) * 32 + g * 8];
#pragma unroll
    for (int m = 0; m < 4; ++m)
#pragma unroll
      for (int n = 0; n < 4; ++n)
        acc[m][n] = __builtin_amdgcn_mfma_f32_16x16x32_bf16(af[m], bfr[n], acc[m][n], 0, 0, 0);

    __syncthreads();  // drains t+1 staging (after compute) + readers done with cur
    cur ^= 1;
  }

#pragma unroll
  for (int m = 0; m < 4; ++m)
#pragma unroll
    for (int n = 0; n < 4; ++n) {
      size_t row = bm + wr * 64 + m * 16 + g * 4;
      size_t col = bn + wc * 64 + n * 16 + lx;
#pragma unroll
      for (int j = 0; j < 4; ++j)
        C[(row + j) * N + col] = (OutT)acc[m][n][j];
    }
}

// ---------------- fused cast+projections: q = Q@wq ; [k|v] = [K;V]@[wk|wv] --------
// 2-phase + T14 split on the reg-staged A path.
__global__ __launch_bounds__(256)
void proj_kernel(const float* __restrict__ Qf, const float* __restrict__ Kf,
                 const float* __restrict__ Vf, const bf16* __restrict__ wqT,
                 const bf16* __restrict__ wkvT, bf16* __restrict__ qp,
                 bf16* __restrict__ kp, bf16* __restrict__ vTp) {
  const int bid = blockIdx.x;
  const bool isq = bid < 512;
  const float* Af;
  size_t arow, bm, bn;
  const bf16* Bt = isq ? wqT : wkvT;
  if (isq) {
    bm = (size_t)(bid & 63) * 128;
    arow = bm;
    bn = (size_t)(bid >> 6) * 128;
    Af = Qf;
  } else {
    int kv = bid - 512;  // 0..127 rows of stacked [K;V]
    bm = (size_t)kv * 128;
    bn = 0;
    if (kv < 64) { Af = Kf; arow = bm; } else { Af = Vf; arow = bm - 8192; }
  }

  __shared__ __align__(16) bf16 As[2][128 * 32];
  __shared__ __align__(16) bf16 Bs[2][128 * 32];
  const int tid = threadIdx.x;
  const int wid = tid >> 6, lane = tid & 63;
  const int wr = wid >> 1, wc = wid & 1;
  const int lx = lane & 15, g = lane >> 4;
  f32x4 acc[4][4] = {};

  auto loadA = [&](int k0, float4 (&ar)[2][2]) {
#pragma unroll
    for (int i = 0; i < 2; ++i) {
      int c = i * 256 + tid;
      const float* src = Af + (arow + (size_t)(c >> 2)) * 1024 + k0 + (c & 3) * 8;
      ar[i][0] = *(const float4*)src;
      ar[i][1] = *(const float4*)(src + 4);
    }
  };
  auto writeA = [&](int buf, const float4 (&ar)[2][2]) {
#pragma unroll
    for (int i = 0; i < 2; ++i) {
      bf16x8 v;
      v[0] = (bf16)ar[i][0].x; v[1] = (bf16)ar[i][0].y;
      v[2] = (bf16)ar[i][0].z; v[3] = (bf16)ar[i][0].w;
      v[4] = (bf16)ar[i][1].x; v[5] = (bf16)ar[i][1].y;
      v[6] = (bf16)ar[i][1].z; v[7] = (bf16)ar[i][1].w;
      *(bf16x8*)((char*)As[buf] + (size_t)(i * 256 + tid) * 16) = v;
    }
  };
  auto stageB = [&](int buf, int k0) {
#pragma unroll
    for (int i = 0; i < 2; ++i) {
      int c = i * 256 + wid * 64 + lane;
      const bf16* gp = Bt + (bn + (size_t)(c >> 2)) * 1024 + k0 + (c & 3) * 8;
      gload_lds16(gp, (char*)Bs[buf] + (size_t)(i * 256 + wid * 64) * 16);
    }
  };

  // prologue: tile 0
  {
    float4 ar[2][2];
    loadA(0, ar);
    stageB(0, 0);
    writeA(0, ar);
  }
  __syncthreads();
  int cur = 0;

  for (int t = 0; t < 32; ++t) {
    float4 ar[2][2];
    const bool more = t + 1 < 32;
    if (more) {
      loadA((t + 1) * 32, ar);   // issue fp32 loads early (T14)
      stageB(cur ^ 1, (t + 1) * 32);
    }

    bf16x8 af[4], bfr[4];
#pragma unroll
    for (int m = 0; m < 4; ++m)
      af[m] = *(const bf16x8*)&As[cur][(wr * 64 + m * 16 + lx) * 32 + g * 8];
#pragma unroll
    for (int n = 0; n < 4; ++n)
      bfr[n] = *(const bf16x8*)&Bs[cur][(wc * 64 + n * 16 + lx) * 32 + g * 8];
#pragma unroll
    for (int m = 0; m < 4; ++m)
#pragma unroll
      for (int n = 0; n < 4; ++n)
        acc[m][n] = __builtin_amdgcn_mfma_f32_16x16x32_bf16(af[m], bfr[n], acc[m][n], 0, 0, 0);

    if (more) writeA(cur ^ 1, ar);  // vmcnt wait + convert AFTER compute

    __syncthreads();  // drains B staging + A writes; readers done with cur
    cur ^= 1;
  }

#pragma unroll
  for (int m = 0; m < 4; ++m)
#pragma unroll
    for (int n = 0; n < 4; ++n) {
      size_t row = bm + wr * 64 + m * 16 + g * 4;
      size_t col = bn + wc * 64 + n * 16 + lx;
#pragma unroll
      for (int j = 0; j < 4; ++j) {
        float v = acc[m][n][j];
        size_t r = row + j;
        if (isq) {
          qp[r * 1024 + col] = (bf16)v;
        } else if (col < 64) {
          if (r < 8192) kp[r * 64 + col] = (bf16)v;  // [b*2048+key][64]
        } else {
          if (r >= 8192) {
            size_t rr = r - 8192;
            size_t bb = rr >> 11, nn = rr & 2047;
            vTp[bb * 131072 + (nn >> 5) * 2048 + (col - 64) * 32 + (nn & 31)] = (bf16)v;
          }
        }
      }
    }
}

// ---------------- causal multi-query flash attention (r8 config + r16/r17 ILP) ----
// grid (32 strip-pairs, 4 head-groups, 4 batch) = 512 blocks, 4 waves = 4 HEADS.
// r16: 4-chain row-max tree; loadV hoisted before softmax.
// r17: per-subtile softmax->PV interleave -- A's 4 PV MFMAs issue between A's and
// B's softmax so the MFMA pipe runs under B's VALU work (m114: separate pipes);
// ls chains split into 2 independent partials. Same math, same sync structure.
__global__ __launch_bounds__(256, 2)
void attn_kernel(const bf16* __restrict__ q, const bf16* __restrict__ k,
                 const bf16* __restrict__ vt, bf16* __restrict__ o) {
  const int hg = blockIdx.y, b = blockIdx.z;
  const int wid = threadIdx.x >> 6, lane = threadIdx.x & 63;
  const int lq = lane & 31, hi = lane >> 5;
  const int h = hg * 4 + wid;
  const int pairIdx = blockIdx.x;  // 0..31

  __shared__ __align__(16) char Ks[2][8192];  // 2 x 4KB subtiles (32 keys x 64d each)
  __shared__ __align__(16) char Vs[2][8192];  // 2 x 4KB subtiles (64d x 32 keys each)
  __shared__ float bc[4][32];

  const bf16* kb = k + (size_t)b * 2048 * 64;                // [key][64]
  const char* vbase = (const char*)vt + (size_t)b * 262144;  // [tile][d][key32]

  // stage one 4KB K tile kt into buffer bi, subtile sub (swizzle at SOURCE, rule 21)
  auto stageK = [&](int bi, int kt, int sub) {
    int src = (wid * 64 + lane) ^ ((lane >> 3) & 7);
    gload_lds16((const char*)(kb + (size_t)kt * 2048) + src * 16,
                &Ks[bi][sub * 4096 + wid * 1024]);
  };
  auto stageV = [&](int bi, int kt, int sub) {
    int g = wid * 64 + lane;
    int src = (g & ~3) | ((g & 3) ^ ((lane >> 3) & 3));
    gload_lds16(vbase + (size_t)kt * 4096 + src * 16, &Vs[bi][sub * 4096 + wid * 1024]);
  };

  bf16x8 qf[4];

  // QK^T for one 32-key subtile: S^T[key][q], lane holds 16 scores of query lq,
  // key = base + (r&3)+8*(r>>2)+4*hi
  auto qkt = [&](int cur, int sub) -> f32x16 {
    bf16x8 kf[4];
#pragma unroll
    for (int i = 0; i < 4; ++i)
      kf[i] = *(const bf16x8*)&Ks[cur][sub * 4096 + ((lq * 8 + i * 2 + hi) ^ (lq & 7)) * 16];
    f32x16 S = {};
#pragma unroll
    for (int i = 0; i < 4; ++i)
      S = __builtin_amdgcn_mfma_f32_32x32x16_bf16(kf[i], qf[i], S, 0, 0, 0);
    return S;
  };
  auto loadV = [&](int cur, int sub, bf16x8 (&vf)[2][2]) {
#pragma unroll
    for (int d = 0; d < 2; ++d)
#pragma unroll
      for (int ks = 0; ks < 2; ++ks)
        vf[d][ks] = *(const bf16x8*)&Vs[cur][sub * 4096 +
                        ((d * 32 + lq) * 4 + ((ks * 2 + hi) ^ ((lq >> 1) & 3))) * 16];
  };
  // 16-value max as two independent 8-chains (ILP 2, max3-fusable triples)
  auto vmax16 = [&](const f32x16& S) -> float {
    float a = fmaxf(fmaxf(S[0], S[1]), S[2]);
    a = fmaxf(fmaxf(a, S[3]), S[4]);
    a = fmaxf(fmaxf(a, S[5]), S[6]);
    a = fmaxf(a, S[7]);
    float c = fmaxf(fmaxf(S[8], S[9]), S[10]);
    c = fmaxf(fmaxf(c, S[11]), S[12]);
    c = fmaxf(fmaxf(c, S[13]), S[14]);
    c = fmaxf(c, S[15]);
    return fmaxf(a, c);
  };
  // exp2 + pack with 2 independent sum partials; returns tile l-sum
  auto expPack = [&](const f32x16& S, float mm, u32 (&wv)[8]) -> float {
    float s0 = 0.f, s1 = 0.f;
#pragma unroll
    for (int i = 0; i < 4; ++i) {
      float e0 = __builtin_amdgcn_exp2f(S[2 * i] - mm);
      float e1 = __builtin_amdgcn_exp2f(S[2 * i + 1] - mm);
      s0 += e0 + e1;
      wv[i] = pack2(e0, e1);
    }
#pragma unroll
    for (int i = 4; i < 8; ++i) {
      float e0 = __builtin_amdgcn_exp2f(S[2 * i] - mm);
      float e1 = __builtin_amdgcn_exp2f(S[2 * i + 1] - mm);
      s1 += e0 + e1;
      wv[i] = pack2(e0, e1);
    }
    return s0 + s1;
  };
  // rebuild PV A-fragments from 8 packed words (verified round-2 path)
  auto rebuild = [&](const u32 w[8], bf16x8& o0, bf16x8& o1) {
    u32 sw0 = (u32)__shfl_xor((int)w[0], 32), sw1 = (u32)__shfl_xor((int)w[1], 32);
    u32 sw2 = (u32)__shfl_xor((int)w[2], 32), sw3 = (u32)__shfl_xor((int)w[3], 32);
    u32 sw4 = (u32)__shfl_xor((int)w[4], 32), sw5 = (u32)__shfl_xor((int)w[5], 32);
    u32 sw6 = (u32)__shfl_xor((int)w[6], 32), sw7 = (u32)__shfl_xor((int)w[7], 32);
    union { u32 d[4]; bf16x8 v; } f0, f1;
    f0.d[0] = hi ? sw2 : w[0];
    f0.d[1] = hi ? sw3 : w[1];
    f0.d[2] = hi ? w[2] : sw0;
    f0.d[3] = hi ? w[3] : sw1;
    f1.d[0] = hi ? sw6 : w[4];
    f1.d[1] = hi ? sw7 : w[5];
    f1.d[2] = hi ? w[6] : sw4;
    f1.d[3] = hi ? w[7] : sw5;
    o0 = f0.v;
    o1 = f1.v;
  };

#pragma unroll 1
  for (int rep = 0; rep < 2; ++rep) {
    const int strip = rep ? pairIdx : 63 - pairIdx;
    const int qb = strip * 32;
    const int nt = strip + 1;
    const int nfull = nt >> 1, tail = nt & 1;

    const bf16* qrow = q + (size_t)(b * 2048 + qb + lq) * 1024 + h * 64 + hi * 8;
#pragma unroll
    for (int i = 0; i < 4; ++i) qf[i] = *(const bf16x8*)(qrow + i * 16);

    f32x16 O0 = {}, O1 = {};
    float m = -__builtin_inff(), l = 0.f;

    __syncthreads();  // previous rep's readers done before restaging buffers
    if (nfull) {
      stageK(0, 0, 0); stageK(0, 1, 1);
      stageV(0, 0, 0); stageV(0, 1, 1);
    } else {
      stageK(0, 0, 0); stageV(0, 0, 0);
    }
    __syncthreads();
    int cur = 0;

    for (int r2 = 0; r2 < nfull; ++r2) {
      if (r2 + 1 < nfull) {
        stageK(cur ^ 1, 2 * r2 + 2, 0); stageK(cur ^ 1, 2 * r2 + 3, 1);
        stageV(cur ^ 1, 2 * r2 + 2, 0); stageV(cur ^ 1, 2 * r2 + 3, 1);
      } else if (tail) {
        stageK(cur ^ 1, 2 * nfull, 0); stageV(cur ^ 1, 2 * nfull, 0);
      }

      __builtin_amdgcn_s_setprio(1);
      f32x16 SA = qkt(cur, 0);
      f32x16 SB = qkt(cur, 1);
      __builtin_amdgcn_s_setprio(0);

      // hoist V reads: ds_read latency hides under the softmax VALU below
      bf16x8 vfA[2][2], vfB[2][2];
      loadV(cur, 0, vfA);
      loadV(cur, 1, vfB);

      if (r2 == nfull - 1 && !tail) {  // subtile B is the diagonal tile
#pragma unroll
        for (int r = 0; r < 16; ++r) {
          int kr = (r & 3) + 8 * (r >> 2) + 4 * hi;
          if (kr > lq) SB[r] = -__builtin_inff();
        }
      }

      // joint row max: 4 independent 8-chains, depth-2 combine
      float pmA = vmax16(SA);
      float pmB = vmax16(SB);
      float pm = fmaxf(pmA, pmB);
      pm = fmaxf(pm, __shfl_xor(pm, 32));

      if (!__all(pm <= m + 8.0f)) {  // rescale path (rare after warmup)
        float mn = fmaxf(m, pm);
        float fac = __builtin_amdgcn_exp2f(m - mn);
        m = mn;
        l *= fac;
        if (hi == 0) bc[wid][lq] = fac;
        __threadfence_block();
#pragma unroll
        for (int r = 0; r < 16; ++r) {
          float fr = bc[wid][(r & 3) + 8 * (r >> 2) + 4 * hi];
          O0[r] *= fr;
          O1[r] *= fr;
        }
      }

      // ---- subtile A: softmax -> PV (MFMA pipe runs under B's VALU below) ----
      u32 wA[8];
      float lsA = expPack(SA, m, wA);
      bf16x8 f0A, f1A;
      rebuild(wA, f0A, f1A);
      __builtin_amdgcn_s_setprio(1);
      O0 = __builtin_amdgcn_mfma_f32_32x32x16_bf16(f0A, vfA[0][0], O0, 0, 0, 0);
      O0 = __builtin_amdgcn_mfma_f32_32x32x16_bf16(f1A, vfA[0][1], O0, 0, 0, 0);
      O1 = __builtin_amdgcn_mfma_f32_32x32x16_bf16(f0A, vfA[1][0], O1, 0, 0, 0);
      O1 = __builtin_amdgcn_mfma_f32_32x32x16_bf16(f1A, vfA[1][1], O1, 0, 0, 0);
      __builtin_amdgcn_s_setprio(0);

      // ---- subtile B: softmax -> PV ----
      u32 wB[8];
      float lsB = expPack(SB, m, wB);
      bf16x8 f0B, f1B;
      rebuild(wB, f0B, f1B);
      __builtin_amdgcn_s_setprio(1);
      O0 = __builtin_amdgcn_mfma_f32_32x32x16_bf16(f0B, vfB[0][0], O0, 0, 0, 0);
      O0 = __builtin_amdgcn_mfma_f32_32x32x16_bf16(f1B, vfB[0][1], O0, 0, 0, 0);
      O1 = __builtin_amdgcn_mfma_f32_32x32x16_bf16(f0B, vfB[1][0], O1, 0, 0, 0);
      O1 = __builtin_amdgcn_mfma_f32_32x32x16_bf16(f1B, vfB[1][1], O1, 0, 0, 0);
      __builtin_amdgcn_s_setprio(0);

      float ls = lsA + lsB;
      ls += __shfl_xor(ls, 32);
      l += ls;

      __syncthreads();  // own staging drained + all waves done reading
      cur ^= 1;
    }

    if (tail) {  // final 32-key diagonal tile (nt odd), staged in buffer `cur` sub 0
      __builtin_amdgcn_s_setprio(1);
      f32x16 S = qkt(cur, 0);
      __builtin_amdgcn_s_setprio(0);
      bf16x8 vf[2][2];
      loadV(cur, 0, vf);
#pragma unroll
      for (int r = 0; r < 16; ++r) {
        int kr = (r & 3) + 8 * (r >> 2) + 4 * hi;
        if (kr > lq) S[r] = -__builtin_inff();
      }
      float pm = vmax16(S);
      pm = fmaxf(pm, __shfl_xor(pm, 32));

      if (!__all(pm <= m + 8.0f)) {
        float mn = fmaxf(m, pm);
        float fac = __builtin_amdgcn_exp2f(m - mn);
        m = mn;
        l *= fac;
        if (hi == 0) bc[wid][lq] = fac;
        __threadfence_block();
#pragma unroll
        for (int r = 0; r < 16; ++r) {
          float fr = bc[wid][(r & 3) + 8 * (r >> 2) + 4 * hi];
          O0[r] *= fr;
          O1[r] *= fr;
        }
      }

      u32 w[8];
      float ls = expPack(S, m, w);
      ls += __shfl_xor(ls, 32);
      l += ls;

      bf16x8 f0, f1;
      rebuild(w, f0, f1);

      __builtin_amdgcn_s_setprio(1);
      O0 = __builtin_amdgcn_mfma_f32_32x32x16_bf16(f0, vf[0][0], O0, 0, 0, 0);
      O0 = __builtin_amdgcn_mfma_f32_32x32x16_bf16(f1, vf[0][1], O0, 0, 0, 0);
      O1 = __builtin_amdgcn_mfma_f32_32x32x16_bf16(f0, vf[1][0], O1, 0, 0, 0);
      O1 = __builtin_amdgcn_mfma_f32_32x32x16_bf16(f1, vf[1][1], O1, 0, 0, 0);
      __builtin_amdgcn_s_setprio(0);
    }

    // epilogue: normalize by 1/l (broadcast per output row) and store
    float linv = 1.0f / l;
    if (hi == 0) bc[wid][lq] = linv;
    __threadfence_block();
#pragma unroll
    for (int r = 0; r < 16; ++r) {
      int row = (r & 3) + 8 * (r >> 2) + 4 * hi;
      float sc = bc[wid][row];
      size_t base = (size_t)(b * 2048 + qb + row) * 1024 + h * 64;
      o[base + lq] = (bf16)(O0[r] * sc);
      o[base + 32 + lq] = (bf16)(O1[r] * sc);
    }
  }
}

// ---------------- launch ----------------
extern "C" void kernel_launch(void* const* d_in, const int* in_sizes, int n_in,
                              void* d_out, int out_size, void* d_ws, size_t ws_size,
                              hipStream_t stream) {
  const float* Q  = (const float*)d_in[0];
  const float* K  = (const float*)d_in[1];
  const float* V  = (const float*)d_in[2];
  const float* wq = (const float*)d_in[3];
  const float* wk = (const float*)d_in[4];
  const float* wv = (const float*)d_in[5];
  const float* wo = (const float*)d_in[6];
  float* out = (float*)d_out;

  char* ws = (char*)d_ws;
  bf16* qp   = (bf16*)(ws + (48ull << 20));          // q proj bf16, 16 MB
  bf16* ab   = (bf16*)(ws + (64ull << 20));          // attn out bf16, 16 MB
  bf16* kp   = (bf16*)(ws + (80ull << 20));          // [b][key][64], 1 MB
  bf16* vTp  = (bf16*)(ws + (81ull << 20));          // [b][tile][d][key32], 1 MB
  bf16* wqT  = (bf16*)(ws + (82ull << 20));          // 2 MB
  bf16* woT  = (bf16*)(ws + (84ull << 20));          // 2 MB
  bf16* wkvT = (bf16*)(ws + (86ull << 20));          // [128][1024] = 256 KB

  // fold softmax scale (1/sqrt(64)) and log2(e) into Wq (exp2-based softmax)
  const float SCALE = 0.125f * 1.44269504088896340736f;
  transpose_all<<<dim3(68, 32), 256, 0, stream>>>(wq, wk, wv, wo, wqT, wkvT, woT, SCALE);

  proj_kernel<<<640, 256, 0, stream>>>(Q, K, V, wqT, wkvT, qp, kp, vTp);

  attn_kernel<<<dim3(32, 4, 4), 256, 0, stream>>>(qp, kp, vTp, ab);

  gemm_bt<float><<<dim3(64, 8), 256, 0, stream>>>(ab, woT, out, 8192, 1024, 1024);
}

// Round 18
// 150.137 us; speedup vs baseline: 1.3009x; 1.0012x over previous
//
#include <hip/hip_runtime.h>

typedef __bf16 bf16;
typedef unsigned int u32;
typedef __bf16 bf16x8 __attribute__((ext_vector_type(8)));
typedef float f32x4 __attribute__((ext_vector_type(4)));
typedef float f32x16 __attribute__((ext_vector_type(16)));

#define DEV __device__ __forceinline__

// async global->LDS, 16B per lane; lds base must be wave-uniform (HW adds lane*16);
// global source address IS per-lane (m173)
DEV void gload_lds16(const void* g, void* l) {
  __builtin_amdgcn_global_load_lds((const __attribute__((address_space(1))) void*)g,
                                   (__attribute__((address_space(3))) void*)l,
                                   16, 0, 0);
}

DEV u32 pack2(float a, float b) {
  unsigned short ua = __builtin_bit_cast(unsigned short, (bf16)a);
  unsigned short ub = __builtin_bit_cast(unsigned short, (bf16)b);
  return (u32)ua | ((u32)ub << 16);
}

// ---------------- all weight transposes in ONE launch ----------------
__global__ void transpose_all(const float* __restrict__ wq, const float* __restrict__ wk,
                              const float* __restrict__ wv, const float* __restrict__ wo,
                              bf16* __restrict__ wqT, bf16* __restrict__ wkvT,
                              bf16* __restrict__ woT, float scale_q) {
  __shared__ float tile[32][33];
  int x = blockIdx.x;
  const float* in;
  bf16* out;
  int C;
  float scale = 1.0f;
  int c0;
  if (x < 32)      { in = wq; out = wqT;             C = 1024; c0 = x * 32; scale = scale_q; }
  else if (x < 34) { in = wk; out = wkvT;            C = 64;   c0 = (x - 32) * 32; }
  else if (x < 36) { in = wv; out = wkvT + 64 * 1024; C = 64;  c0 = (x - 34) * 32; }
  else             { in = wo; out = woT;             C = 1024; c0 = (x - 36) * 32; }
  int r0 = blockIdx.y * 32;
  int tx = threadIdx.x & 31, ty = threadIdx.x >> 5;  // 256 threads = 32x8
  for (int i = ty; i < 32; i += 8) tile[i][tx] = in[(size_t)(r0 + i) * C + c0 + tx];
  __syncthreads();
  for (int i = ty; i < 32; i += 8)
    out[(size_t)(c0 + i) * 1024 + r0 + tx] = (bf16)(tile[tx][i] * scale);
}

// ---------------- bf16 GEMM, B transposed (Bt[N][K]), 2-phase ----------------
template <typename OutT>
__global__ __launch_bounds__(256)
void gemm_bt(const bf16* __restrict__ A, const bf16* __restrict__ Bt,
             OutT* __restrict__ C, int M, int N, int K) {
  __shared__ __align__(16) bf16 As[2][128 * 32];
  __shared__ __align__(16) bf16 Bs[2][128 * 32];
  const int tid = threadIdx.x;
  const int wid = tid >> 6, lane = tid & 63;
  const int wr = wid >> 1, wc = wid & 1;
  const int lx = lane & 15, g = lane >> 4;
  const size_t bm = (size_t)blockIdx.x * 128;
  const size_t bn = (size_t)blockIdx.y * 128;
  f32x4 acc[4][4] = {};
  const int nk = K >> 5;

  auto stage = [&](int buf, int k0) {
#pragma unroll
    for (int i = 0; i < 2; ++i) {
      int c = i * 256 + wid * 64 + lane;
      const bf16* gp = A + (bm + (size_t)(c >> 2)) * K + k0 + (c & 3) * 8;
      gload_lds16(gp, (char*)As[buf] + (size_t)(i * 256 + wid * 64) * 16);
    }
#pragma unroll
    for (int i = 0; i < 2; ++i) {
      int c = i * 256 + wid * 64 + lane;
      const bf16* gp = Bt + (bn + (size_t)(c >> 2)) * K + k0 + (c & 3) * 8;
      gload_lds16(gp, (char*)Bs[buf] + (size_t)(i * 256 + wid * 64) * 16);
    }
  };

  stage(0, 0);
  __syncthreads();
  int cur = 0;

  for (int t = 0; t < nk; ++t) {
    if (t + 1 < nk) stage(cur ^ 1, (t + 1) * 32);

    bf16x8 af[4], bfr[4];
#pragma unroll
    for (int m = 0; m < 4; ++m)
      af[m] = *(const bf16x8*)&As[cur][(wr * 64 + m * 16 + lx) * 32 + g * 8];
#pragma unroll
    for (int n = 0; n < 4; ++n)
      bfr[n] = *(const bf16x8*)&Bs[cur][(wc * 64 + n * 16 + lx) * 32 + g * 8];
#pragma unroll
    for (int m = 0; m < 4; ++m)
#pragma unroll
      for (int n = 0; n < 4; ++n)
        acc[m][n] = __builtin_amdgcn_mfma_f32_16x16x32_bf16(af[m], bfr[n], acc[m][n], 0, 0, 0);

    __syncthreads();  // drains t+1 staging (after compute) + readers done with cur
    cur ^= 1;
  }

#pragma unroll
  for (int m = 0; m < 4; ++m)
#pragma unroll
    for (int n = 0; n < 4; ++n) {
      size_t row = bm + wr * 64 + m * 16 + g * 4;
      size_t col = bn + wc * 64 + n * 16 + lx;
#pragma unroll
      for (int j = 0; j < 4; ++j)
        C[(row + j) * N + col] = (OutT)acc[m][n][j];
    }
}

// ---------------- fused cast+projections: q = Q@wq ; [k|v] = [K;V]@[wk|wv] --------
// 2-phase + T14 split on the reg-staged A path.
__global__ __launch_bounds__(256)
void proj_kernel(const float* __restrict__ Qf, const float* __restrict__ Kf,
                 const float* __restrict__ Vf, const bf16* __restrict__ wqT,
                 const bf16* __restrict__ wkvT, bf16* __restrict__ qp,
                 bf16* __restrict__ kp, bf16* __restrict__ vTp) {
  const int bid = blockIdx.x;
  const bool isq = bid < 512;
  const float* Af;
  size_t arow, bm, bn;
  const bf16* Bt = isq ? wqT : wkvT;
  if (isq) {
    bm = (size_t)(bid & 63) * 128;
    arow = bm;
    bn = (size_t)(bid >> 6) * 128;
    Af = Qf;
  } else {
    int kv = bid - 512;  // 0..127 rows of stacked [K;V]
    bm = (size_t)kv * 128;
    bn = 0;
    if (kv < 64) { Af = Kf; arow = bm; } else { Af = Vf; arow = bm - 8192; }
  }

  __shared__ __align__(16) bf16 As[2][128 * 32];
  __shared__ __align__(16) bf16 Bs[2][128 * 32];
  const int tid = threadIdx.x;
  const int wid = tid >> 6, lane = tid & 63;
  const int wr = wid >> 1, wc = wid & 1;
  const int lx = lane & 15, g = lane >> 4;
  f32x4 acc[4][4] = {};

  auto loadA = [&](int k0, float4 (&ar)[2][2]) {
#pragma unroll
    for (int i = 0; i < 2; ++i) {
      int c = i * 256 + tid;
      const float* src = Af + (arow + (size_t)(c >> 2)) * 1024 + k0 + (c & 3) * 8;
      ar[i][0] = *(const float4*)src;
      ar[i][1] = *(const float4*)(src + 4);
    }
  };
  auto writeA = [&](int buf, const float4 (&ar)[2][2]) {
#pragma unroll
    for (int i = 0; i < 2; ++i) {
      bf16x8 v;
      v[0] = (bf16)ar[i][0].x; v[1] = (bf16)ar[i][0].y;
      v[2] = (bf16)ar[i][0].z; v[3] = (bf16)ar[i][0].w;
      v[4] = (bf16)ar[i][1].x; v[5] = (bf16)ar[i][1].y;
      v[6] = (bf16)ar[i][1].z; v[7] = (bf16)ar[i][1].w;
      *(bf16x8*)((char*)As[buf] + (size_t)(i * 256 + tid) * 16) = v;
    }
  };
  auto stageB = [&](int buf, int k0) {
#pragma unroll
    for (int i = 0; i < 2; ++i) {
      int c = i * 256 + wid * 64 + lane;
      const bf16* gp = Bt + (bn + (size_t)(c >> 2)) * 1024 + k0 + (c & 3) * 8;
      gload_lds16(gp, (char*)Bs[buf] + (size_t)(i * 256 + wid * 64) * 16);
    }
  };

  // prologue: tile 0
  {
    float4 ar[2][2];
    loadA(0, ar);
    stageB(0, 0);
    writeA(0, ar);
  }
  __syncthreads();
  int cur = 0;

  for (int t = 0; t < 32; ++t) {
    float4 ar[2][2];
    const bool more = t + 1 < 32;
    if (more) {
      loadA((t + 1) * 32, ar);   // issue fp32 loads early (T14)
      stageB(cur ^ 1, (t + 1) * 32);
    }

    bf16x8 af[4], bfr[4];
#pragma unroll
    for (int m = 0; m < 4; ++m)
      af[m] = *(const bf16x8*)&As[cur][(wr * 64 + m * 16 + lx) * 32 + g * 8];
#pragma unroll
    for (int n = 0; n < 4; ++n)
      bfr[n] = *(const bf16x8*)&Bs[cur][(wc * 64 + n * 16 + lx) * 32 + g * 8];
#pragma unroll
    for (int m = 0; m < 4; ++m)
#pragma unroll
      for (int n = 0; n < 4; ++n)
        acc[m][n] = __builtin_amdgcn_mfma_f32_16x16x32_bf16(af[m], bfr[n], acc[m][n], 0, 0, 0);

    if (more) writeA(cur ^ 1, ar);  // vmcnt wait + convert AFTER compute

    __syncthreads();  // drains B staging + A writes; readers done with cur
    cur ^= 1;
  }

#pragma unroll
  for (int m = 0; m < 4; ++m)
#pragma unroll
    for (int n = 0; n < 4; ++n) {
      size_t row = bm + wr * 64 + m * 16 + g * 4;
      size_t col = bn + wc * 64 + n * 16 + lx;
#pragma unroll
      for (int j = 0; j < 4; ++j) {
        float v = acc[m][n][j];
        size_t r = row + j;
        if (isq) {
          qp[r * 1024 + col] = (bf16)v;
        } else if (col < 64) {
          if (r < 8192) kp[r * 64 + col] = (bf16)v;  // [b*2048+key][64]
        } else {
          if (r >= 8192) {
            size_t rr = r - 8192;
            size_t bb = rr >> 11, nn = rr & 2047;
            vTp[bb * 131072 + (nn >> 5) * 2048 + (col - 64) * 32 + (nn & 31)] = (bf16)v;
          }
        }
      }
    }
}

// ---------------- causal multi-query flash attention (r8 + r16/r17/r18 ILP) ----
// grid (32 strip-pairs, 4 head-groups, 4 batch) = 512 blocks, 4 waves = 4 HEADS.
// r16: 4-chain row-max tree; loadV hoisted before softmax.
// r17: per-subtile softmax->PV interleave (MFMA pipe under VALU work, m114).
// r18: rescale/epilogue row-broadcasts via __shfl (fac, 1/l are lane-symmetric
//      across the 32-boundary after the shfl_xor(32) reduce; pattern validated in
//      r14's kernel) -- removes the bc[] LDS round-trip + threadfence.
__global__ __launch_bounds__(256, 2)
void attn_kernel(const bf16* __restrict__ q, const bf16* __restrict__ k,
                 const bf16* __restrict__ vt, bf16* __restrict__ o) {
  const int hg = blockIdx.y, b = blockIdx.z;
  const int wid = threadIdx.x >> 6, lane = threadIdx.x & 63;
  const int lq = lane & 31, hi = lane >> 5;
  const int h = hg * 4 + wid;
  const int pairIdx = blockIdx.x;  // 0..31

  __shared__ __align__(16) char Ks[2][8192];  // 2 x 4KB subtiles (32 keys x 64d each)
  __shared__ __align__(16) char Vs[2][8192];  // 2 x 4KB subtiles (64d x 32 keys each)

  const bf16* kb = k + (size_t)b * 2048 * 64;                // [key][64]
  const char* vbase = (const char*)vt + (size_t)b * 262144;  // [tile][d][key32]

  // stage one 4KB K tile kt into buffer bi, subtile sub (swizzle at SOURCE, rule 21)
  auto stageK = [&](int bi, int kt, int sub) {
    int src = (wid * 64 + lane) ^ ((lane >> 3) & 7);
    gload_lds16((const char*)(kb + (size_t)kt * 2048) + src * 16,
                &Ks[bi][sub * 4096 + wid * 1024]);
  };
  auto stageV = [&](int bi, int kt, int sub) {
    int g = wid * 64 + lane;
    int src = (g & ~3) | ((g & 3) ^ ((lane >> 3) & 3));
    gload_lds16(vbase + (size_t)kt * 4096 + src * 16, &Vs[bi][sub * 4096 + wid * 1024]);
  };

  bf16x8 qf[4];

  // QK^T for one 32-key subtile: S^T[key][q], lane holds 16 scores of query lq,
  // key = base + (r&3)+8*(r>>2)+4*hi
  auto qkt = [&](int cur, int sub) -> f32x16 {
    bf16x8 kf[4];
#pragma unroll
    for (int i = 0; i < 4; ++i)
      kf[i] = *(const bf16x8*)&Ks[cur][sub * 4096 + ((lq * 8 + i * 2 + hi) ^ (lq & 7)) * 16];
    f32x16 S = {};
#pragma unroll
    for (int i = 0; i < 4; ++i)
      S = __builtin_amdgcn_mfma_f32_32x32x16_bf16(kf[i], qf[i], S, 0, 0, 0);
    return S;
  };
  auto loadV = [&](int cur, int sub, bf16x8 (&vf)[2][2]) {
#pragma unroll
    for (int d = 0; d < 2; ++d)
#pragma unroll
      for (int ks = 0; ks < 2; ++ks)
        vf[d][ks] = *(const bf16x8*)&Vs[cur][sub * 4096 +
                        ((d * 32 + lq) * 4 + ((ks * 2 + hi) ^ ((lq >> 1) & 3))) * 16];
  };
  // 16-value max as two independent 8-chains (ILP 2, max3-fusable triples)
  auto vmax16 = [&](const f32x16& S) -> float {
    float a = fmaxf(fmaxf(S[0], S[1]), S[2]);
    a = fmaxf(fmaxf(a, S[3]), S[4]);
    a = fmaxf(fmaxf(a, S[5]), S[6]);
    a = fmaxf(a, S[7]);
    float c = fmaxf(fmaxf(S[8], S[9]), S[10]);
    c = fmaxf(fmaxf(c, S[11]), S[12]);
    c = fmaxf(fmaxf(c, S[13]), S[14]);
    c = fmaxf(c, S[15]);
    return fmaxf(a, c);
  };
  // exp2 + pack with 2 independent sum partials; returns tile l-sum
  auto expPack = [&](const f32x16& S, float mm, u32 (&wv)[8]) -> float {
    float s0 = 0.f, s1 = 0.f;
#pragma unroll
    for (int i = 0; i < 4; ++i) {
      float e0 = __builtin_amdgcn_exp2f(S[2 * i] - mm);
      float e1 = __builtin_amdgcn_exp2f(S[2 * i + 1] - mm);
      s0 += e0 + e1;
      wv[i] = pack2(e0, e1);
    }
#pragma unroll
    for (int i = 4; i < 8; ++i) {
      float e0 = __builtin_amdgcn_exp2f(S[2 * i] - mm);
      float e1 = __builtin_amdgcn_exp2f(S[2 * i + 1] - mm);
      s1 += e0 + e1;
      wv[i] = pack2(e0, e1);
    }
    return s0 + s1;
  };
  // rebuild PV A-fragments from 8 packed words (verified round-2 path)
  auto rebuild = [&](const u32 w[8], bf16x8& o0, bf16x8& o1) {
    u32 sw0 = (u32)__shfl_xor((int)w[0], 32), sw1 = (u32)__shfl_xor((int)w[1], 32);
    u32 sw2 = (u32)__shfl_xor((int)w[2], 32), sw3 = (u32)__shfl_xor((int)w[3], 32);
    u32 sw4 = (u32)__shfl_xor((int)w[4], 32), sw5 = (u32)__shfl_xor((int)w[5], 32);
    u32 sw6 = (u32)__shfl_xor((int)w[6], 32), sw7 = (u32)__shfl_xor((int)w[7], 32);
    union { u32 d[4]; bf16x8 v; } f0, f1;
    f0.d[0] = hi ? sw2 : w[0];
    f0.d[1] = hi ? sw3 : w[1];
    f0.d[2] = hi ? w[2] : sw0;
    f0.d[3] = hi ? w[3] : sw1;
    f1.d[0] = hi ? sw6 : w[4];
    f1.d[1] = hi ? sw7 : w[5];
    f1.d[2] = hi ? w[6] : sw4;
    f1.d[3] = hi ? w[7] : sw5;
    o0 = f0.v;
    o1 = f1.v;
  };

#pragma unroll 1
  for (int rep = 0; rep < 2; ++rep) {
    const int strip = rep ? pairIdx : 63 - pairIdx;
    const int qb = strip * 32;
    const int nt = strip + 1;
    const int nfull = nt >> 1, tail = nt & 1;

    const bf16* qrow = q + (size_t)(b * 2048 + qb + lq) * 1024 + h * 64 + hi * 8;
#pragma unroll
    for (int i = 0; i < 4; ++i) qf[i] = *(const bf16x8*)(qrow + i * 16);

    f32x16 O0 = {}, O1 = {};
    float m = -__builtin_inff(), l = 0.f;

    __syncthreads();  // previous rep's readers done before restaging buffers
    if (nfull) {
      stageK(0, 0, 0); stageK(0, 1, 1);
      stageV(0, 0, 0); stageV(0, 1, 1);
    } else {
      stageK(0, 0, 0); stageV(0, 0, 0);
    }
    __syncthreads();
    int cur = 0;

    for (int r2 = 0; r2 < nfull; ++r2) {
      if (r2 + 1 < nfull) {
        stageK(cur ^ 1, 2 * r2 + 2, 0); stageK(cur ^ 1, 2 * r2 + 3, 1);
        stageV(cur ^ 1, 2 * r2 + 2, 0); stageV(cur ^ 1, 2 * r2 + 3, 1);
      } else if (tail) {
        stageK(cur ^ 1, 2 * nfull, 0); stageV(cur ^ 1, 2 * nfull, 0);
      }

      __builtin_amdgcn_s_setprio(1);
      f32x16 SA = qkt(cur, 0);
      f32x16 SB = qkt(cur, 1);
      __builtin_amdgcn_s_setprio(0);

      // hoist V reads: ds_read latency hides under the softmax VALU below
      bf16x8 vfA[2][2], vfB[2][2];
      loadV(cur, 0, vfA);
      loadV(cur, 1, vfB);

      if (r2 == nfull - 1 && !tail) {  // subtile B is the diagonal tile
#pragma unroll
        for (int r = 0; r < 16; ++r) {
          int kr = (r & 3) + 8 * (r >> 2) + 4 * hi;
          if (kr > lq) SB[r] = -__builtin_inff();
        }
      }

      // joint row max: 4 independent 8-chains, depth-2 combine
      float pmA = vmax16(SA);
      float pmB = vmax16(SB);
      float pm = fmaxf(pmA, pmB);
      pm = fmaxf(pm, __shfl_xor(pm, 32));

      if (!__all(pm <= m + 8.0f)) {  // rescale path (rare after warmup)
        float mn = fmaxf(m, pm);
        float fac = __builtin_amdgcn_exp2f(m - mn);
        m = mn;
        l *= fac;
#pragma unroll
        for (int r = 0; r < 16; ++r) {
          float fr = __shfl(fac, (r & 3) + 8 * (r >> 2) + 4 * hi);
          O0[r] *= fr;
          O1[r] *= fr;
        }
      }

      // ---- subtile A: softmax -> PV (MFMA pipe runs under B's VALU below) ----
      u32 wA[8];
      float lsA = expPack(SA, m, wA);
      bf16x8 f0A, f1A;
      rebuild(wA, f0A, f1A);
      __builtin_amdgcn_s_setprio(1);
      O0 = __builtin_amdgcn_mfma_f32_32x32x16_bf16(f0A, vfA[0][0], O0, 0, 0, 0);
      O0 = __builtin_amdgcn_mfma_f32_32x32x16_bf16(f1A, vfA[0][1], O0, 0, 0, 0);
      O1 = __builtin_amdgcn_mfma_f32_32x32x16_bf16(f0A, vfA[1][0], O1, 0, 0, 0);
      O1 = __builtin_amdgcn_mfma_f32_32x32x16_bf16(f1A, vfA[1][1], O1, 0, 0, 0);
      __builtin_amdgcn_s_setprio(0);

      // ---- subtile B: softmax -> PV ----
      u32 wB[8];
      float lsB = expPack(SB, m, wB);
      bf16x8 f0B, f1B;
      rebuild(wB, f0B, f1B);
      __builtin_amdgcn_s_setprio(1);
      O0 = __builtin_amdgcn_mfma_f32_32x32x16_bf16(f0B, vfB[0][0], O0, 0, 0, 0);
      O0 = __builtin_amdgcn_mfma_f32_32x32x16_bf16(f1B, vfB[0][1], O0, 0, 0, 0);
      O1 = __builtin_amdgcn_mfma_f32_32x32x16_bf16(f0B, vfB[1][0], O1, 0, 0, 0);
      O1 = __builtin_amdgcn_mfma_f32_32x32x16_bf16(f1B, vfB[1][1], O1, 0, 0, 0);
      __builtin_amdgcn_s_setprio(0);

      float ls = lsA + lsB;
      ls += __shfl_xor(ls, 32);
      l += ls;

      __syncthreads();  // own staging drained + all waves done reading
      cur ^= 1;
    }

    if (tail) {  // final 32-key diagonal tile (nt odd), staged in buffer `cur` sub 0
      __builtin_amdgcn_s_setprio(1);
      f32x16 S = qkt(cur, 0);
      __builtin_amdgcn_s_setprio(0);
      bf16x8 vf[2][2];
      loadV(cur, 0, vf);
#pragma unroll
      for (int r = 0; r < 16; ++r) {
        int kr = (r & 3) + 8 * (r >> 2) + 4 * hi;
        if (kr > lq) S[r] = -__builtin_inff();
      }
      float pm = vmax16(S);
      pm = fmaxf(pm, __shfl_xor(pm, 32));

      if (!__all(pm <= m + 8.0f)) {
        float mn = fmaxf(m, pm);
        float fac = __builtin_amdgcn_exp2f(m - mn);
        m = mn;
        l *= fac;
#pragma unroll
        for (int r = 0; r < 16; ++r) {
          float fr = __shfl(fac, (r & 3) + 8 * (r >> 2) + 4 * hi);
          O0[r] *= fr;
          O1[r] *= fr;
        }
      }

      u32 w[8];
      float ls = expPack(S, m, w);
      ls += __shfl_xor(ls, 32);
      l += ls;

      bf16x8 f0, f1;
      rebuild(w, f0, f1);

      __builtin_amdgcn_s_setprio(1);
      O0 = __builtin_amdgcn_mfma_f32_32x32x16_bf16(f0, vf[0][0], O0, 0, 0, 0);
      O0 = __builtin_amdgcn_mfma_f32_32x32x16_bf16(f1, vf[0][1], O0, 0, 0, 0);
      O1 = __builtin_amdgcn_mfma_f32_32x32x16_bf16(f0, vf[1][0], O1, 0, 0, 0);
      O1 = __builtin_amdgcn_mfma_f32_32x32x16_bf16(f1, vf[1][1], O1, 0, 0, 0);
      __builtin_amdgcn_s_setprio(0);
    }

    // epilogue: normalize by 1/l (row broadcast via shfl) and store
    float linv = 1.0f / l;
#pragma unroll
    for (int r = 0; r < 16; ++r) {
      int row = (r & 3) + 8 * (r >> 2) + 4 * hi;
      float sc = __shfl(linv, row);
      size_t base = (size_t)(b * 2048 + qb + row) * 1024 + h * 64;
      o[base + lq] = (bf16)(O0[r] * sc);
      o[base + 32 + lq] = (bf16)(O1[r] * sc);
    }
  }
}

// ---------------- launch ----------------
extern "C" void kernel_launch(void* const* d_in, const int* in_sizes, int n_in,
                              void* d_out, int out_size, void* d_ws, size_t ws_size,
                              hipStream_t stream) {
  const float* Q  = (const float*)d_in[0];
  const float* K  = (const float*)d_in[1];
  const float* V  = (const float*)d_in[2];
  const float* wq = (const float*)d_in[3];
  const float* wk = (const float*)d_in[4];
  const float* wv = (const float*)d_in[5];
  const float* wo = (const float*)d_in[6];
  float* out = (float*)d_out;

  char* ws = (char*)d_ws;
  bf16* qp   = (bf16*)(ws + (48ull << 20));          // q proj bf16, 16 MB
  bf16* ab   = (bf16*)(ws + (64ull << 20));          // attn out bf16, 16 MB
  bf16* kp   = (bf16*)(ws + (80ull << 20));          // [b][key][64], 1 MB
  bf16* vTp  = (bf16*)(ws + (81ull << 20));          // [b][tile][d][key32], 1 MB
  bf16* wqT  = (bf16*)(ws + (82ull << 20));          // 2 MB
  bf16* woT  = (bf16*)(ws + (84ull << 20));          // 2 MB
  bf16* wkvT = (bf16*)(ws + (86ull << 20));          // [128][1024] = 256 KB

  // fold softmax scale (1/sqrt(64)) and log2(e) into Wq (exp2-based softmax)
  const float SCALE = 0.125f * 1.44269504088896340736f;
  transpose_all<<<dim3(68, 32), 256, 0, stream>>>(wq, wk, wv, wo, wqT, wkvT, woT, SCALE);

  proj_kernel<<<640, 256, 0, stream>>>(Q, K, V, wqT, wkvT, qp, kp, vTp);

  attn_kernel<<<dim3(32, 4, 4), 256, 0, stream>>>(qp, kp, vTp, ab);

  gemm_bt<float><<<dim3(64, 8), 256, 0, stream>>>(ab, woT, out, 8192, 1024, 1024);
}